// Round 7
// baseline (10483.877 us; speedup 1.0000x reference)
//
#include <hip/hip_runtime.h>

typedef unsigned short u16;
typedef unsigned int   u32;

__device__ __forceinline__ u16 f2b(float f) {        // RNE via hw cvt
  __bf16 h = (__bf16)f; u16 u; __builtin_memcpy(&u, &h, 2); return u;
}
__device__ __forceinline__ float b2f(u16 u) {
  u32 i = ((u32)u) << 16; float f; __builtin_memcpy(&f, &i, 4); return f;
}

// workspace accessors templated on element width
template<int F32> __device__ __forceinline__ float ws_ld(const void* p, size_t i) {
  return F32 ? ((const float*)p)[i] : b2f(((const u16*)p)[i]);
}
template<int F32> __device__ __forceinline__ void ws_st(void* p, size_t i, float v) {
  if (F32) ((float*)p)[i] = v; else ((u16*)p)[i] = f2b(v);
}

// ---------------------------------------------------------------------------
// Naive 16x16-tile fp32 gemm (verified round 6):
// C[m,n] = dot(A[m,:], B[n,:]) + bias[n].
// A: f32 (AF32) or ws element. C: f32 (CF32) or ws element.
// B/bias fp32, selected per 1024-col segment (fused QKV).
// ---------------------------------------------------------------------------
template<int AF32, int CF32>
__global__ __launch_bounds__(256) void gemm_naive(
    const void* __restrict__ Av,
    const float* __restrict__ B0, const float* __restrict__ B1, const float* __restrict__ B2,
    const float* __restrict__ bias0, const float* __restrict__ bias1, const float* __restrict__ bias2,
    void* __restrict__ C, int M, int K, int ldc)
{
  __shared__ float As[16][17];
  __shared__ float Bs[16][17];
  const int tx = threadIdx.x, ty = threadIdx.y;   // block (16,16)
  const int m  = blockIdx.x * 16 + ty;
  const int n0 = blockIdx.y * 16;
  const int seg = n0 >> 10, nl = n0 & 1023;
  const float* B    = seg == 0 ? B0    : (seg == 1 ? B1    : B2);
  const float* bias = seg == 0 ? bias0 : (seg == 1 ? bias1 : bias2);

  float acc = 0.0f;
  for (int k0 = 0; k0 < K; k0 += 16) {
    As[ty][tx] = ws_ld<AF32>(Av, (size_t)m * K + k0 + tx);
    Bs[ty][tx] = B[(size_t)(nl + ty) * K + k0 + tx];
    __syncthreads();
#pragma unroll
    for (int kk = 0; kk < 16; ++kk) acc += As[ty][kk] * Bs[tx][kk];
    __syncthreads();
  }
  ws_st<CF32>(C, (size_t)m * ldc + n0 + tx, acc + bias[nl + tx]);
}

// ---------------------------------------------------------------------------
// Naive RMSNorm in qkv ws: one thread per (token, q|k, head).
// ---------------------------------------------------------------------------
template<int WSF32>
__global__ __launch_bounds__(256) void rmsnorm_naive(
    void* __restrict__ qkv, const float* __restrict__ qn, const float* __restrict__ kn, int T)
{
  int id = blockIdx.x * 256 + threadIdx.x;
  if (id >= T * 32) return;
  int tok = id >> 5, rem = id & 31;
  int which = rem >> 4, head = rem & 15;     // which: 0=q, 1=k
  size_t base = (size_t)tok * 3072 + which * 1024 + head * 64;
  float ss = 0.0f;
  for (int d = 0; d < 64; ++d) { float f = ws_ld<WSF32>(qkv, base + d); ss += f * f; }
  float sc = rsqrtf(ss * (1.0f / 64.0f) + 1.1920929e-07f);
  const float* w = which ? kn : qn;
  for (int d = 0; d < 64; ++d)
    ws_st<WSF32>(qkv, base + d, ws_ld<WSF32>(qkv, base + d) * sc * w[d]);
}

// ---------------------------------------------------------------------------
// Naive attention (verified round 5/6): one wave per (token, head);
// lane = head dim; fp32 math; two-pass softmax through LDS.
// ---------------------------------------------------------------------------
template<int WSF32, int AOF32>
__global__ __launch_bounds__(64) void attn_naive(
    const void* __restrict__ qkv, const int* __restrict__ cu, int nseq,
    void* __restrict__ out)
{
  __shared__ float sc[1024];                // len <= LMAX
  const int t = blockIdx.x;                 // global token
  const int head = blockIdx.y;
  const int lane = threadIdx.x;             // 0..63 = head dim

  int start = 0, end = 0;
  for (int i = 0; i < nseq; ++i) {
    if (t >= cu[i] && t < cu[i + 1]) { start = cu[i]; end = cu[i + 1]; }
  }
  const int len = end - start;

  const float qd = ws_ld<WSF32>(qkv, (size_t)t * 3072 + head * 64 + lane);

  for (int s = 0; s < len; ++s) {           // scores
    float part = qd * ws_ld<WSF32>(qkv, (size_t)(start + s) * 3072 + 1024 + head * 64 + lane);
    part += __shfl_xor(part, 1);
    part += __shfl_xor(part, 2);
    part += __shfl_xor(part, 4);
    part += __shfl_xor(part, 8);
    part += __shfl_xor(part, 16);
    part += __shfl_xor(part, 32);
    if (lane == 0) sc[s] = part * 0.125f;
  }
  __syncthreads();

  float m = -1e30f;                          // softmax
  for (int i = lane; i < len; i += 64) m = fmaxf(m, sc[i]);
  m = fmaxf(m, __shfl_xor(m, 1));
  m = fmaxf(m, __shfl_xor(m, 2));
  m = fmaxf(m, __shfl_xor(m, 4));
  m = fmaxf(m, __shfl_xor(m, 8));
  m = fmaxf(m, __shfl_xor(m, 16));
  m = fmaxf(m, __shfl_xor(m, 32));
  float sum = 0.0f;
  for (int i = lane; i < len; i += 64) {
    float e = __expf(sc[i] - m);
    sc[i] = e;
    sum += e;
  }
  __syncthreads();
  sum += __shfl_xor(sum, 1);
  sum += __shfl_xor(sum, 2);
  sum += __shfl_xor(sum, 4);
  sum += __shfl_xor(sum, 8);
  sum += __shfl_xor(sum, 16);
  sum += __shfl_xor(sum, 32);
  const float inv = 1.0f / sum;

  float o = 0.0f;                            // PV
  for (int s = 0; s < len; ++s) {
    o += sc[s] * ws_ld<WSF32>(qkv, (size_t)(start + s) * 3072 + 2048 + head * 64 + lane);
  }
  ws_st<AOF32>(out, (size_t)t * 1024 + head * 64 + lane, o * inv);
}

// sentinel: distinct failure signature if workspace is too small (f32 1024.0)
__global__ void ws_too_small_sentinel(float* out) {
  if (threadIdx.x == 0 && blockIdx.x == 0) out[0] = 1024.0f;
}

// ---------------------------------------------------------------------------
extern "C" void kernel_launch(void* const* d_in, const int* in_sizes, int n_in,
                              void* d_out, int out_size, void* d_ws, size_t ws_size,
                              hipStream_t stream) {
  const float* x  = (const float*)d_in[0];   // inputs fp32 (per reference)
  const int*   cu = (const int*)d_in[1];
  const float* Wq = (const float*)d_in[2];
  const float* bq = (const float*)d_in[3];
  const float* Wk = (const float*)d_in[4];
  const float* bk = (const float*)d_in[5];
  const float* Wv = (const float*)d_in[6];
  const float* bv = (const float*)d_in[7];
  const float* qn = (const float*)d_in[8];
  const float* kn = (const float*)d_in[9];
  const float* Wo = (const float*)d_in[10];
  const float* bo = (const float*)d_in[11];

  const int T = in_sizes[0] / 1024;
  const int nseq = in_sizes[1] - 1;

  // EXPERIMENT ROUND: output written as FP32 (theory T2: reference output
  // dtype is f32; the bf16 label refers to comparison thresholding only).
  const size_t need_f32f32 = (size_t)T * 3072 * 4 + (size_t)T * 1024 * 4; // 134 MB
  const size_t need_b16f32 = (size_t)T * 3072 * 2 + (size_t)T * 1024 * 4; //  84 MB
  const size_t need_b16b16 = (size_t)T * 3072 * 2 + (size_t)T * 1024 * 2; //  67 MB

  dim3 gblk(16, 16);
  dim3 g1(T / 16, 3072 / 16), g2(T / 16, 1024 / 16);
  dim3 rng((T * 32 + 255) / 256), rnb(256);
  dim3 ag(T, 16), ab(64);

  if (ws_size >= need_f32f32) {            // tier 1: all-f32 ws (error ~1e-4)
    float* qkv  = (float*)d_ws;
    float* attn = qkv + (size_t)T * 3072;
    gemm_naive<1, 1><<<g1, gblk, 0, stream>>>(x, Wq, Wk, Wv, bq, bk, bv, qkv, T, 1024, 3072);
    rmsnorm_naive<1><<<rng, rnb, 0, stream>>>(qkv, qn, kn, T);
    attn_naive<1, 1><<<ag, ab, 0, stream>>>(qkv, cu, nseq, attn);
    gemm_naive<1, 1><<<g2, gblk, 0, stream>>>(attn, Wo, Wo, Wo, bo, bo, bo, d_out, T, 1024, 1024);
  } else if (ws_size >= need_b16f32) {     // tier 2: bf16 qkv, f32 attn ws
    u16*   qkv  = (u16*)d_ws;
    float* attn = (float*)(qkv + (size_t)T * 3072);
    gemm_naive<1, 0><<<g1, gblk, 0, stream>>>(x, Wq, Wk, Wv, bq, bk, bv, qkv, T, 1024, 3072);
    rmsnorm_naive<0><<<rng, rnb, 0, stream>>>(qkv, qn, kn, T);
    attn_naive<0, 1><<<ag, ab, 0, stream>>>(qkv, cu, nseq, attn);
    gemm_naive<1, 1><<<g2, gblk, 0, stream>>>(attn, Wo, Wo, Wo, bo, bo, bo, d_out, T, 1024, 1024);
  } else if (ws_size >= need_b16b16) {     // tier 3: bf16 ws (round-6 noise)
    u16* qkv  = (u16*)d_ws;
    u16* attn = qkv + (size_t)T * 3072;
    gemm_naive<1, 0><<<g1, gblk, 0, stream>>>(x, Wq, Wk, Wv, bq, bk, bv, qkv, T, 1024, 3072);
    rmsnorm_naive<0><<<rng, rnb, 0, stream>>>(qkv, qn, kn, T);
    attn_naive<0, 0><<<ag, ab, 0, stream>>>(qkv, cu, nseq, attn);
    gemm_naive<0, 1><<<g2, gblk, 0, stream>>>(attn, Wo, Wo, Wo, bo, bo, bo, d_out, T, 1024, 1024);
  } else {
    ws_too_small_sentinel<<<1, 64, 0, stream>>>((float*)d_out);
  }
}

// Round 8
// 469.647 us; speedup vs baseline: 22.3229x; 22.3229x over previous
//
#include <hip/hip_runtime.h>

typedef unsigned short u16;
typedef unsigned int   u32;

typedef __bf16 bf16x8_t __attribute__((ext_vector_type(8)));
typedef bf16x8_t bf16x8 __attribute__((may_alias));
typedef float f32x4_t __attribute__((ext_vector_type(4)));
typedef f32x4_t f32x4 __attribute__((may_alias));
typedef u32 u32x4_t __attribute__((ext_vector_type(4)));
typedef u32x4_t u32x4 __attribute__((may_alias));

__device__ __forceinline__ u16 f2b(float f) {        // RNE via hw cvt
  __bf16 h = (__bf16)f; u16 u; __builtin_memcpy(&u, &h, 2); return u;
}
__device__ __forceinline__ float b2f(u16 u) {
  u32 i = ((u32)u) << 16; float f; __builtin_memcpy(&f, &i, 4); return f;
}
// load 8 consecutive f32, convert to bf16x8 (two dwordx4 loads + 8 v_cvt)
__device__ __forceinline__ bf16x8_t cvt8(const float* p) {
  f32x4_t a = *(const f32x4*)p;
  f32x4_t b = *(const f32x4*)(p + 4);
  bf16x8_t v;
  v[0]=(__bf16)a[0]; v[1]=(__bf16)a[1]; v[2]=(__bf16)a[2]; v[3]=(__bf16)a[3];
  v[4]=(__bf16)b[0]; v[5]=(__bf16)b[1]; v[6]=(__bf16)b[2]; v[7]=(__bf16)b[3];
  return v;
}

// ---------------------------------------------------------------------------
// C = A(MxK) @ B(NxK)^T + bias, fp32 accum, bf16 MFMA.
// A fp32 (AF32=1) or bf16 ws. C fp32 (CF32=1, for d_out) or bf16 ws.
// B/bias fp32, selected per 1024-col segment (fused QKV).
// m92/m93 structure: 128x128 tile, BK=32, reg->LDS staging, 16x16x32 MFMA,
// C/D map col=lane&15, row=quad*4+reg (m89/m91).
// ---------------------------------------------------------------------------
#define BK 32
template<int AF32, int CF32>
__global__ __launch_bounds__(256, 2) void gemm_bt(
    const void* __restrict__ Av,
    const float* __restrict__ B0, const float* __restrict__ B1, const float* __restrict__ B2,
    const float* __restrict__ bias0, const float* __restrict__ bias1, const float* __restrict__ bias2,
    void* __restrict__ C, int M, int K, int ldc)
{
  __shared__ alignas(16) u16 As[128 * BK];
  __shared__ alignas(16) u16 Bs[128 * BK];
  const int t = threadIdx.x;
  const int lane = t & 63, wave = t >> 6;
  const int quad = lane >> 4, col = lane & 15;
  const int m0 = blockIdx.x * 128, n0 = blockIdx.y * 128;
  const int seg = n0 >> 10;
  const float* B    = seg == 0 ? B0    : (seg == 1 ? B1    : B2);
  const float* bias = seg == 0 ? bias0 : (seg == 1 ? bias1 : bias2);
  const int nl0 = n0 & 1023;
  const int wm = (wave >> 1) * 64, wn = (wave & 1) * 64;

  const int lrow = t >> 2;
  const int lcol = (t & 3) * 8;              // element offset of 8-elem chunk
  int ar0 = m0 + lrow;      if (ar0 >= M) ar0 = M - 1;
  int ar1 = m0 + 64 + lrow; if (ar1 >= M) ar1 = M - 1;
  const float* bp0 = B + (size_t)(nl0 + lrow) * K + lcol;
  const float* bp1 = B + (size_t)(nl0 + 64 + lrow) * K + lcol;
  const float* apf0 = (const float*)Av + (size_t)ar0 * K + lcol;
  const float* apf1 = (const float*)Av + (size_t)ar1 * K + lcol;
  const u16*   aph0 = (const u16*)Av   + (size_t)ar0 * K + lcol;
  const u16*   aph1 = (const u16*)Av   + (size_t)ar1 * K + lcol;
  u16* lA0 = As + t * 8;
  u16* lA1 = As + 64 * BK + t * 8;
  u16* lB0 = Bs + t * 8;
  u16* lB1 = Bs + 64 * BK + t * 8;

  f32x4_t acc[4][4] = {};
  for (int k0 = 0; k0 < K; k0 += BK) {
    bf16x8_t va0, va1, vb0, vb1;
    if (AF32) {
      va0 = cvt8(apf0 + k0);
      va1 = cvt8(apf1 + k0);
    } else {
      u32x4_t r0 = *(const u32x4*)(aph0 + k0);
      u32x4_t r1 = *(const u32x4*)(aph1 + k0);
      __builtin_memcpy(&va0, &r0, 16);
      __builtin_memcpy(&va1, &r1, 16);
    }
    vb0 = cvt8(bp0 + k0);
    vb1 = cvt8(bp1 + k0);
    __syncthreads();
    *(bf16x8*)lA0 = va0;
    *(bf16x8*)lA1 = va1;
    *(bf16x8*)lB0 = vb0;
    *(bf16x8*)lB1 = vb1;
    __syncthreads();
    bf16x8 af[4], bfr[4];
#pragma unroll
    for (int i = 0; i < 4; ++i) {
      af[i]  = *(const bf16x8*)(As + (wm + i * 16 + col) * BK + quad * 8);
      bfr[i] = *(const bf16x8*)(Bs + (wn + i * 16 + col) * BK + quad * 8);
    }
#pragma unroll
    for (int i = 0; i < 4; ++i)
#pragma unroll
      for (int j = 0; j < 4; ++j)
        acc[i][j] = __builtin_amdgcn_mfma_f32_16x16x32_bf16(af[i], bfr[j], acc[i][j], 0, 0, 0);
  }

#pragma unroll
  for (int j = 0; j < 4; ++j) {
    int gn = n0 + wn + j * 16 + col;
    float bz = bias[nl0 + wn + j * 16 + col];
#pragma unroll
    for (int i = 0; i < 4; ++i) {
#pragma unroll
      for (int rr = 0; rr < 4; ++rr) {
        int gm = m0 + wm + i * 16 + quad * 4 + rr;   // D row = quad*4+reg
        if (gm < M) {
          float v = acc[i][j][rr] + bz;
          if (CF32) ((float*)C)[(size_t)gm * ldc + gn] = v;
          else      ((u16*)C)[(size_t)gm * ldc + gn] = f2b(v);
        }
      }
    }
  }
}

// ---------------------------------------------------------------------------
// In-place RMSNorm of q,k heads in bf16 qkv ws; weights fp32. (r4 kernel)
// ---------------------------------------------------------------------------
__global__ __launch_bounds__(256) void rmsnorm_qk(
    u16* __restrict__ qkv, const float* __restrict__ qn, const float* __restrict__ kn, int T)
{
  int gid = blockIdx.x * 256 + threadIdx.x;
  int row = gid >> 4, sub = gid & 15;
  if (row >= 2 * T * 16) return;
  int which = row >= T * 16;               // 0 = q, 1 = k
  int r = which ? row - T * 16 : row;
  int tok = r >> 4, head = r & 15;
  u16* p = qkv + (size_t)tok * 3072 + which * 1024 + head * 64 + sub * 4;
  u16 d0 = p[0], d1 = p[1], d2 = p[2], d3 = p[3];
  float f0 = b2f(d0), f1 = b2f(d1), f2v = b2f(d2), f3 = b2f(d3);
  float ss = f0 * f0 + f1 * f1 + f2v * f2v + f3 * f3;
  ss += __shfl_xor(ss, 1);
  ss += __shfl_xor(ss, 2);
  ss += __shfl_xor(ss, 4);
  ss += __shfl_xor(ss, 8);
  float sc = rsqrtf(ss * (1.0f / 64.0f) + 1.1920929e-07f);
  const float* w = which ? kn : qn;
  p[0] = f2b(f0 * sc * w[sub * 4 + 0]);
  p[1] = f2b(f1 * sc * w[sub * 4 + 1]);
  p[2] = f2b(f2v * sc * w[sub * 4 + 2]);
  p[3] = f2b(f3 * sc * w[sub * 4 + 3]);
}

// ---------------------------------------------------------------------------
// Flash attention (r4 MFMA kernel): block = (64-row qtile, head, seq);
// 4 waves x 16 q-rows. 32-key KV tiles in LDS (K stride 72, V^T stride 40).
// QK^T 2x2 mfma -> online softmax -> P via per-wave LDS C->A transform
// (m120) -> PV 4x mfma. Output bf16 ws.
// ---------------------------------------------------------------------------
#define NEG 30000.0f
__global__ __launch_bounds__(256, 2) void attn_fwd(
    const u16* __restrict__ qkv, const int* __restrict__ cu, u16* __restrict__ out)
{
  __shared__ alignas(16) u16 Ks[32 * 72];
  __shared__ alignas(16) u16 Vts[64 * 40];
  __shared__ alignas(16) u16 Ps[4 * 16 * 40];
  const int seq = blockIdx.z, head = blockIdx.y, qt = blockIdx.x;
  const int start = cu[seq], len = cu[seq + 1] - start;
  const int q0 = qt * 64;
  if (q0 >= len) return;                    // block-uniform exit, pre-barrier
  const int t = threadIdx.x;
  const int lane = t & 63, wave = t >> 6, quad = lane >> 4, col = lane & 15;

  int qrow = q0 + wave * 16 + col;
  int tq = start + (qrow < len ? qrow : len - 1);
  const u16* qp = qkv + (size_t)tq * 3072 + head * 64 + quad * 8;
  bf16x8 qf0 = *(const bf16x8*)qp;          // A-frag k=0..31
  bf16x8 qf1 = *(const bf16x8*)(qp + 32);   // A-frag k=32..63

  f32x4_t accO[4] = {};
  float m_[4] = {-NEG, -NEG, -NEG, -NEG};
  float l_[4] = {};
  const float SC = 0.125f * 1.44269504089f; // 1/sqrt(64) * log2(e)

  const int skv = t >> 3, scc = t & 7;
  const int nkv = (len + 31) >> 5;
  for (int it = 0; it < nkv; ++it) {
    int k0 = it << 5;
    __syncthreads();
    {
      int tk = start + (k0 + skv < len ? k0 + skv : len - 1);
      const u16* kp = qkv + (size_t)tk * 3072 + 1024 + head * 64 + scc * 8;
      *(u32x4*)(Ks + skv * 72 + scc * 8) = *(const u32x4*)kp;     // K natural
      u32x4_t dv = *(const u32x4*)(kp + 1024);                    // V row chunk
#pragma unroll
      for (int j = 0; j < 4; ++j) {
        u32 w = dv[j];
        Vts[(scc * 8 + 2 * j    ) * 40 + skv] = (u16)(w & 0xffff); // V transposed
        Vts[(scc * 8 + 2 * j + 1) * 40 + skv] = (u16)(w >> 16);
      }
    }
    __syncthreads();

    f32x4_t s0 = {}, s1 = {};
    {
      bf16x8 kb;
      kb = *(const bf16x8*)(Ks + col * 72 + quad * 8);
      s0 = __builtin_amdgcn_mfma_f32_16x16x32_bf16(qf0, kb, s0, 0, 0, 0);
      kb = *(const bf16x8*)(Ks + col * 72 + 32 + quad * 8);
      s0 = __builtin_amdgcn_mfma_f32_16x16x32_bf16(qf1, kb, s0, 0, 0, 0);
      kb = *(const bf16x8*)(Ks + (16 + col) * 72 + quad * 8);
      s1 = __builtin_amdgcn_mfma_f32_16x16x32_bf16(qf0, kb, s1, 0, 0, 0);
      kb = *(const bf16x8*)(Ks + (16 + col) * 72 + 32 + quad * 8);
      s1 = __builtin_amdgcn_mfma_f32_16x16x32_bf16(qf1, kb, s1, 0, 0, 0);
    }
    const bool v0 = (k0 + col) < len;
    const bool v1 = (k0 + 16 + col) < len;
    u16* pw = Ps + wave * 640 + quad * 160 + col;   // row (quad*4+r), stride 40
#pragma unroll
    for (int r = 0; r < 4; ++r) {
      float z0 = v0 ? s0[r] * SC : -NEG;
      float z1 = v1 ? s1[r] * SC : -NEG;
      float mt = fmaxf(z0, z1);
      mt = fmaxf(mt, __shfl_xor(mt, 1));
      mt = fmaxf(mt, __shfl_xor(mt, 2));
      mt = fmaxf(mt, __shfl_xor(mt, 4));
      mt = fmaxf(mt, __shfl_xor(mt, 8));
      float mn = fmaxf(m_[r], mt);
      float al = exp2f(m_[r] - mn);
      float p0 = exp2f(z0 - mn);
      float p1 = exp2f(z1 - mn);
      float rs = p0 + p1;
      rs += __shfl_xor(rs, 1);
      rs += __shfl_xor(rs, 2);
      rs += __shfl_xor(rs, 4);
      rs += __shfl_xor(rs, 8);
      m_[r] = mn;
      l_[r] = l_[r] * al + rs;
      accO[0][r] *= al; accO[1][r] *= al; accO[2][r] *= al; accO[3][r] *= al;
      pw[r * 40]      = f2b(p0);
      pw[r * 40 + 16] = f2b(p1);
    }
    __threadfence_block();   // order P ds_writes before the A-frag ds_read
    bf16x8 pf = *(const bf16x8*)(Ps + wave * 640 + col * 40 + quad * 8);
#pragma unroll
    for (int c = 0; c < 4; ++c) {
      bf16x8 vf = *(const bf16x8*)(Vts + (c * 16 + col) * 40 + quad * 8);
      accO[c] = __builtin_amdgcn_mfma_f32_16x16x32_bf16(pf, vf, accO[c], 0, 0, 0);
    }
  }

#pragma unroll
  for (int r = 0; r < 4; ++r) {
    int rowq = q0 + wave * 16 + quad * 4 + r;
    if (rowq < len) {
      float inv = 1.0f / l_[r];
      u16* op = out + (size_t)(start + rowq) * 1024 + head * 64 + col;
      op[0]  = f2b(accO[0][r] * inv);
      op[16] = f2b(accO[1][r] * inv);
      op[32] = f2b(accO[2][r] * inv);
      op[48] = f2b(accO[3][r] * inv);
    }
  }
}

// sentinel: distinct failure signature if workspace is too small (f32 1024.0)
__global__ void ws_too_small_sentinel(float* out) {
  if (threadIdx.x == 0 && blockIdx.x == 0) out[0] = 1024.0f;
}

// ---------------------------------------------------------------------------
extern "C" void kernel_launch(void* const* d_in, const int* in_sizes, int n_in,
                              void* d_out, int out_size, void* d_ws, size_t ws_size,
                              hipStream_t stream) {
  const float* x  = (const float*)d_in[0];   // inputs fp32, output fp32 (r7)
  const int*   cu = (const int*)d_in[1];
  const float* Wq = (const float*)d_in[2];
  const float* bq = (const float*)d_in[3];
  const float* Wk = (const float*)d_in[4];
  const float* bk = (const float*)d_in[5];
  const float* Wv = (const float*)d_in[6];
  const float* bv = (const float*)d_in[7];
  const float* qn = (const float*)d_in[8];
  const float* kn = (const float*)d_in[9];
  const float* Wo = (const float*)d_in[10];
  const float* bo = (const float*)d_in[11];

  const int T = in_sizes[0] / 1024;
  const int nseq = in_sizes[1] - 1;

  const size_t need = (size_t)T * 3072 * 2 + (size_t)T * 1024 * 2; // 67 MB bf16 ws
  if (ws_size < need) {
    ws_too_small_sentinel<<<1, 64, 0, stream>>>((float*)d_out);
    return;
  }

  u16* qkv  = (u16*)d_ws;                      // T x 3072 bf16 (q|k|v)
  u16* attn = qkv + (size_t)T * 3072;          // T x 1024 bf16

  dim3 blk(256);
  // fused QKV projection: N = 3072 across Wq|Wk|Wv (A = x fp32 -> bf16 ws)
  gemm_bt<1, 0><<<dim3((T + 127) / 128, 24), blk, 0, stream>>>(
      x, Wq, Wk, Wv, bq, bk, bv, qkv, T, 1024, 3072);
  // rmsnorm on q,k heads (in place, bf16 ws)
  rmsnorm_qk<<<dim3((2 * T * 256 + 255) / 256), blk, 0, stream>>>(qkv, qn, kn, T);
  // varlen MFMA flash attention -> bf16 ws
  attn_fwd<<<dim3(16, 16, nseq), blk, 0, stream>>>(qkv, cu, attn);
  // output projection: A = attn ws (bf16), B = Wo fp32 -> f32 d_out
  gemm_bt<0, 1><<<dim3((T + 127) / 128, 8), blk, 0, stream>>>(
      attn, Wo, Wo, Wo, bo, bo, bo, d_out, T, 1024, 1024);
}

// Round 9
// 369.437 us; speedup vs baseline: 28.3780x; 1.2712x over previous
//
#include <hip/hip_runtime.h>

typedef unsigned short u16;
typedef unsigned int   u32;

typedef __bf16 bf16x8_t __attribute__((ext_vector_type(8)));
typedef bf16x8_t bf16x8 __attribute__((may_alias));
typedef float f32x4_t __attribute__((ext_vector_type(4)));
typedef f32x4_t f32x4 __attribute__((may_alias));
typedef u32 u32x4_t __attribute__((ext_vector_type(4)));
typedef u32x4_t u32x4 __attribute__((may_alias));

__device__ __forceinline__ u16 f2b(float f) {        // RNE via hw cvt
  __bf16 h = (__bf16)f; u16 u; __builtin_memcpy(&u, &h, 2); return u;
}
__device__ __forceinline__ float b2f(u16 u) {
  u32 i = ((u32)u) << 16; float f; __builtin_memcpy(&f, &i, 4); return f;
}
// load 8 consecutive f32, convert to bf16x8 (two dwordx4 loads + 8 v_cvt)
__device__ __forceinline__ bf16x8_t cvt8(const float* p) {
  f32x4_t a = *(const f32x4*)p;
  f32x4_t b = *(const f32x4*)(p + 4);
  bf16x8_t v;
  v[0]=(__bf16)a[0]; v[1]=(__bf16)a[1]; v[2]=(__bf16)a[2]; v[3]=(__bf16)a[3];
  v[4]=(__bf16)b[0]; v[5]=(__bf16)b[1]; v[6]=(__bf16)b[2]; v[7]=(__bf16)b[3];
  return v;
}

// ---------------------------------------------------------------------------
// C = A(MxK) @ B(NxK)^T + bias, fp32 accum, bf16 MFMA. (r8, unchanged)
// ---------------------------------------------------------------------------
#define BK 32
template<int AF32, int CF32>
__global__ __launch_bounds__(256, 2) void gemm_bt(
    const void* __restrict__ Av,
    const float* __restrict__ B0, const float* __restrict__ B1, const float* __restrict__ B2,
    const float* __restrict__ bias0, const float* __restrict__ bias1, const float* __restrict__ bias2,
    void* __restrict__ C, int M, int K, int ldc)
{
  __shared__ alignas(16) u16 As[128 * BK];
  __shared__ alignas(16) u16 Bs[128 * BK];
  const int t = threadIdx.x;
  const int lane = t & 63, wave = t >> 6;
  const int quad = lane >> 4, col = lane & 15;
  const int m0 = blockIdx.x * 128, n0 = blockIdx.y * 128;
  const int seg = n0 >> 10;
  const float* B    = seg == 0 ? B0    : (seg == 1 ? B1    : B2);
  const float* bias = seg == 0 ? bias0 : (seg == 1 ? bias1 : bias2);
  const int nl0 = n0 & 1023;
  const int wm = (wave >> 1) * 64, wn = (wave & 1) * 64;

  const int lrow = t >> 2;
  const int lcol = (t & 3) * 8;
  int ar0 = m0 + lrow;      if (ar0 >= M) ar0 = M - 1;
  int ar1 = m0 + 64 + lrow; if (ar1 >= M) ar1 = M - 1;
  const float* bp0 = B + (size_t)(nl0 + lrow) * K + lcol;
  const float* bp1 = B + (size_t)(nl0 + 64 + lrow) * K + lcol;
  const float* apf0 = (const float*)Av + (size_t)ar0 * K + lcol;
  const float* apf1 = (const float*)Av + (size_t)ar1 * K + lcol;
  const u16*   aph0 = (const u16*)Av   + (size_t)ar0 * K + lcol;
  const u16*   aph1 = (const u16*)Av   + (size_t)ar1 * K + lcol;
  u16* lA0 = As + t * 8;
  u16* lA1 = As + 64 * BK + t * 8;
  u16* lB0 = Bs + t * 8;
  u16* lB1 = Bs + 64 * BK + t * 8;

  f32x4_t acc[4][4] = {};
  for (int k0 = 0; k0 < K; k0 += BK) {
    bf16x8_t va0, va1, vb0, vb1;
    if (AF32) {
      va0 = cvt8(apf0 + k0);
      va1 = cvt8(apf1 + k0);
    } else {
      u32x4_t r0 = *(const u32x4*)(aph0 + k0);
      u32x4_t r1 = *(const u32x4*)(aph1 + k0);
      __builtin_memcpy(&va0, &r0, 16);
      __builtin_memcpy(&va1, &r1, 16);
    }
    vb0 = cvt8(bp0 + k0);
    vb1 = cvt8(bp1 + k0);
    __syncthreads();
    *(bf16x8*)lA0 = va0;
    *(bf16x8*)lA1 = va1;
    *(bf16x8*)lB0 = vb0;
    *(bf16x8*)lB1 = vb1;
    __syncthreads();
    bf16x8 af[4], bfr[4];
#pragma unroll
    for (int i = 0; i < 4; ++i) {
      af[i]  = *(const bf16x8*)(As + (wm + i * 16 + col) * BK + quad * 8);
      bfr[i] = *(const bf16x8*)(Bs + (wn + i * 16 + col) * BK + quad * 8);
    }
#pragma unroll
    for (int i = 0; i < 4; ++i)
#pragma unroll
      for (int j = 0; j < 4; ++j)
        acc[i][j] = __builtin_amdgcn_mfma_f32_16x16x32_bf16(af[i], bfr[j], acc[i][j], 0, 0, 0);
  }

#pragma unroll
  for (int j = 0; j < 4; ++j) {
    int gn = n0 + wn + j * 16 + col;
    float bz = bias[nl0 + wn + j * 16 + col];
#pragma unroll
    for (int i = 0; i < 4; ++i) {
#pragma unroll
      for (int rr = 0; rr < 4; ++rr) {
        int gm = m0 + wm + i * 16 + quad * 4 + rr;   // D row = quad*4+reg
        if (gm < M) {
          float v = acc[i][j][rr] + bz;
          if (CF32) ((float*)C)[(size_t)gm * ldc + gn] = v;
          else      ((u16*)C)[(size_t)gm * ldc + gn] = f2b(v);
        }
      }
    }
  }
}

// ---------------------------------------------------------------------------
// In-place RMSNorm of q,k heads in bf16 qkv ws; weights fp32. (r8, unchanged)
// ---------------------------------------------------------------------------
__global__ __launch_bounds__(256) void rmsnorm_qk(
    u16* __restrict__ qkv, const float* __restrict__ qn, const float* __restrict__ kn, int T)
{
  int gid = blockIdx.x * 256 + threadIdx.x;
  int row = gid >> 4, sub = gid & 15;
  if (row >= 2 * T * 16) return;
  int which = row >= T * 16;               // 0 = q, 1 = k
  int r = which ? row - T * 16 : row;
  int tok = r >> 4, head = r & 15;
  u16* p = qkv + (size_t)tok * 3072 + which * 1024 + head * 64 + sub * 4;
  u16 d0 = p[0], d1 = p[1], d2 = p[2], d3 = p[3];
  float f0 = b2f(d0), f1 = b2f(d1), f2v = b2f(d2), f3 = b2f(d3);
  float ss = f0 * f0 + f1 * f1 + f2v * f2v + f3 * f3;
  ss += __shfl_xor(ss, 1);
  ss += __shfl_xor(ss, 2);
  ss += __shfl_xor(ss, 4);
  ss += __shfl_xor(ss, 8);
  float sc = rsqrtf(ss * (1.0f / 64.0f) + 1.1920929e-07f);
  const float* w = which ? kn : qn;
  p[0] = f2b(f0 * sc * w[sub * 4 + 0]);
  p[1] = f2b(f1 * sc * w[sub * 4 + 1]);
  p[2] = f2b(f2v * sc * w[sub * 4 + 2]);
  p[3] = f2b(f3 * sc * w[sub * 4 + 3]);
}

// ---------------------------------------------------------------------------
// Flash attention v2: 64-key tiles, NO online softmax (post-rmsnorm scores
// are bounded: |s| <= 8*max|qn|*max|kn| => exp2 arg <= ~12, fp32 sum safe;
// softmax is shift-invariant so accuracy is unchanged). Row-sum l via a
// ones-row appended to V^T (extra PV MFMA) — zero shuffles in the K-loop.
// Conflict-free LDS strides: Ks 68 (2-way), Vts 66 (~2-way), Ps 68 (free).
// ---------------------------------------------------------------------------
#define SKS 68   // Ks row stride (u16): banks (2c+4q)%32 -> 2-way (free, m136)
#define SVS 66   // Vts row stride: odd dwords break the scatter collapse
#define SPS 68   // Ps row stride: P writes land on all 32 banks
__global__ __launch_bounds__(256, 2) void attn_fwd(
    const u16* __restrict__ qkv, const int* __restrict__ cu, u16* __restrict__ out)
{
  __shared__ alignas(16) u16 Ks[64 * SKS];          // [key][dim]
  __shared__ alignas(16) u16 Vts[80 * SVS];         // [dim][key]; row 64 = ones
  __shared__ alignas(16) u16 Ps[4 * 16 * SPS];      // per-wave [query][key]
  const int seq = blockIdx.z, head = blockIdx.y, qt = blockIdx.x;
  const int start = cu[seq], len = cu[seq + 1] - start;
  const int q0 = qt * 64;
  if (q0 >= len) return;                    // block-uniform exit, pre-barrier
  const int t = threadIdx.x;
  const int lane = t & 63, wave = t >> 6, quad = lane >> 4, col = lane & 15;

  // init ones row (dim 64) + zero rows 65..79 once; ordered by staging barrier
  {
    int rr = 64 + (t >> 4), ccol = (t & 15) * 4;
    u16 v = (t >> 4) == 0 ? (u16)0x3F80 : (u16)0;   // bf16 1.0 : 0.0
    u16* p = Vts + rr * SVS + ccol;
    p[0] = v; p[1] = v; p[2] = v; p[3] = v;
  }

  int qrow = q0 + wave * 16 + col;
  int tq = start + (qrow < len ? qrow : len - 1);
  const u16* qp = qkv + (size_t)tq * 3072 + head * 64 + quad * 8;
  bf16x8 qf0 = *(const bf16x8*)qp;          // A-frag k=0..31
  bf16x8 qf1 = *(const bf16x8*)(qp + 32);   // A-frag k=32..63

  f32x4_t accO[4] = {};
  f32x4_t accL = {};                         // col 0 = row-sum of P
  const float SC = 0.125f * 1.44269504089f;  // 1/sqrt(64) * log2(e)

  const int kv = t >> 2, cc = t & 3;         // staging: key row, 16-dim chunk
  const int nkv = (len + 63) >> 6;
  for (int it = 0; it < nkv; ++it) {
    int k0 = it << 6;
    __syncthreads();
    {
      int tk = start + (k0 + kv < len ? k0 + kv : len - 1);
      const u16* kp = qkv + (size_t)tk * 3072 + 1024 + head * 64 + cc * 16;
      u32x4_t ka = *(const u32x4*)kp;             // K dims cc*16..+7
      u32x4_t kb2 = *(const u32x4*)(kp + 8);      // K dims +8..+15
      u32x4_t va = *(const u32x4*)(kp + 1024);    // V dims cc*16..+7
      u32x4_t vb = *(const u32x4*)(kp + 1032);
      *(u32x4*)(Ks + kv * SKS + cc * 16)     = ka;
      *(u32x4*)(Ks + kv * SKS + cc * 16 + 8) = kb2;
#pragma unroll
      for (int j = 0; j < 4; ++j) {               // V transpose scatter
        u32 w = va[j];
        Vts[(cc*16 + 2*j    ) * SVS + kv] = (u16)(w & 0xffff);
        Vts[(cc*16 + 2*j + 1) * SVS + kv] = (u16)(w >> 16);
        u32 w2 = vb[j];
        Vts[(cc*16 + 8 + 2*j    ) * SVS + kv] = (u16)(w2 & 0xffff);
        Vts[(cc*16 + 8 + 2*j + 1) * SVS + kv] = (u16)(w2 >> 16);
      }
    }
    __syncthreads();

    // S = Q.K^T for 64 keys (4 groups of 16)
    f32x4_t sg[4];
#pragma unroll
    for (int g = 0; g < 4; ++g) {
      f32x4_t s = {};
      bf16x8 kb = *(const bf16x8*)(Ks + (g*16 + col) * SKS + quad * 8);
      s = __builtin_amdgcn_mfma_f32_16x16x32_bf16(qf0, kb, s, 0, 0, 0);
      kb = *(const bf16x8*)(Ks + (g*16 + col) * SKS + 32 + quad * 8);
      s = __builtin_amdgcn_mfma_f32_16x16x32_bf16(qf1, kb, s, 0, 0, 0);
      sg[g] = s;
    }

    // P = exp2(S*SC); mask only ragged tails (lens here are /64)
    const bool full = (k0 + 64 <= len);
    u16* pb = Ps + wave * (16 * SPS);
#pragma unroll
    for (int g = 0; g < 4; ++g) {
      bool vK = full || (k0 + g*16 + col) < len;
#pragma unroll
      for (int r = 0; r < 4; ++r) {
        float p = exp2f(sg[g][r] * SC);
        p = vK ? p : 0.0f;
        pb[(quad*4 + r) * SPS + g*16 + col] = f2b(p);   // C-layout -> [query][key]
      }
    }
    __threadfence_block();   // order P ds_writes before A-frag ds_reads

    bf16x8 pf0 = *(const bf16x8*)(pb + col * SPS + quad * 8);        // keys 0..31
    bf16x8 pf1 = *(const bf16x8*)(pb + col * SPS + 32 + quad * 8);   // keys 32..63
#pragma unroll
    for (int c = 0; c < 4; ++c) {
      bf16x8 vf = *(const bf16x8*)(Vts + (c*16 + col) * SVS + quad * 8);
      accO[c] = __builtin_amdgcn_mfma_f32_16x16x32_bf16(pf0, vf, accO[c], 0, 0, 0);
      vf = *(const bf16x8*)(Vts + (c*16 + col) * SVS + 32 + quad * 8);
      accO[c] = __builtin_amdgcn_mfma_f32_16x16x32_bf16(pf1, vf, accO[c], 0, 0, 0);
    }
    {
      bf16x8 of = *(const bf16x8*)(Vts + (64 + col) * SVS + quad * 8);
      accL = __builtin_amdgcn_mfma_f32_16x16x32_bf16(pf0, of, accL, 0, 0, 0);
      of = *(const bf16x8*)(Vts + (64 + col) * SVS + 32 + quad * 8);
      accL = __builtin_amdgcn_mfma_f32_16x16x32_bf16(pf1, of, accL, 0, 0, 0);
    }
  }

  // epilogue: broadcast l from col 0 of each quad-row, divide, store
#pragma unroll
  for (int r = 0; r < 4; ++r) {
    int rowq = q0 + wave * 16 + quad * 4 + r;
    float l = __shfl(accL[r], lane & 48);   // lane quad*16 holds col 0
    if (rowq < len) {
      float inv = 1.0f / l;
      u16* op = out + (size_t)(start + rowq) * 1024 + head * 64 + col;
      op[0]  = f2b(accO[0][r] * inv);
      op[16] = f2b(accO[1][r] * inv);
      op[32] = f2b(accO[2][r] * inv);
      op[48] = f2b(accO[3][r] * inv);
    }
  }
}

// sentinel: distinct failure signature if workspace is too small (f32 1024.0)
__global__ void ws_too_small_sentinel(float* out) {
  if (threadIdx.x == 0 && blockIdx.x == 0) out[0] = 1024.0f;
}

// ---------------------------------------------------------------------------
extern "C" void kernel_launch(void* const* d_in, const int* in_sizes, int n_in,
                              void* d_out, int out_size, void* d_ws, size_t ws_size,
                              hipStream_t stream) {
  const float* x  = (const float*)d_in[0];   // inputs fp32, output fp32
  const int*   cu = (const int*)d_in[1];
  const float* Wq = (const float*)d_in[2];
  const float* bq = (const float*)d_in[3];
  const float* Wk = (const float*)d_in[4];
  const float* bk = (const float*)d_in[5];
  const float* Wv = (const float*)d_in[6];
  const float* bv = (const float*)d_in[7];
  const float* qn = (const float*)d_in[8];
  const float* kn = (const float*)d_in[9];
  const float* Wo = (const float*)d_in[10];
  const float* bo = (const float*)d_in[11];

  const int T = in_sizes[0] / 1024;
  const int nseq = in_sizes[1] - 1;

  const size_t need = (size_t)T * 3072 * 2 + (size_t)T * 1024 * 2; // 67 MB bf16 ws
  if (ws_size < need) {
    ws_too_small_sentinel<<<1, 64, 0, stream>>>((float*)d_out);
    return;
  }

  u16* qkv  = (u16*)d_ws;                      // T x 3072 bf16 (q|k|v)
  u16* attn = qkv + (size_t)T * 3072;          // T x 1024 bf16

  dim3 blk(256);
  // fused QKV projection: N = 3072 across Wq|Wk|Wv (A = x fp32 -> bf16 ws)
  gemm_bt<1, 0><<<dim3((T + 127) / 128, 24), blk, 0, stream>>>(
      x, Wq, Wk, Wv, bq, bk, bv, qkv, T, 1024, 3072);
  // rmsnorm on q,k heads (in place, bf16 ws)
  rmsnorm_qk<<<dim3((2 * T * 256 + 255) / 256), blk, 0, stream>>>(qkv, qn, kn, T);
  // varlen MFMA flash attention (64-key tiles) -> bf16 ws
  attn_fwd<<<dim3(16, 16, nseq), blk, 0, stream>>>(qkv, cu, attn);
  // output projection: A = attn ws (bf16), B = Wo fp32 -> f32 d_out
  gemm_bt<0, 1><<<dim3((T + 127) / 128, 8), blk, 0, stream>>>(
      attn, Wo, Wo, Wo, bo, bo, bo, d_out, T, 1024, 1024);
}

// Round 10
// 318.937 us; speedup vs baseline: 32.8713x; 1.1583x over previous
//
#include <hip/hip_runtime.h>

typedef unsigned short u16;
typedef unsigned int   u32;

typedef __bf16 bf16x8_t __attribute__((ext_vector_type(8)));
typedef bf16x8_t bf16x8 __attribute__((may_alias));
typedef float f32x4_t __attribute__((ext_vector_type(4)));
typedef f32x4_t f32x4 __attribute__((may_alias));
typedef u32 u32x4_t __attribute__((ext_vector_type(4)));
typedef u32x4_t u32x4 __attribute__((may_alias));
typedef u32 u32x2_t __attribute__((ext_vector_type(2)));
typedef u32x2_t u32x2 __attribute__((may_alias));

__device__ __forceinline__ u16 f2b(float f) {        // RNE via hw cvt
  __bf16 h = (__bf16)f; u16 u; __builtin_memcpy(&u, &h, 2); return u;
}
__device__ __forceinline__ float b2f(u16 u) {
  u32 i = ((u32)u) << 16; float f; __builtin_memcpy(&f, &i, 4); return f;
}
__device__ __forceinline__ bf16x8_t cvt8(const float* p) {
  f32x4_t a = *(const f32x4*)p;
  f32x4_t b = *(const f32x4*)(p + 4);
  bf16x8_t v;
  v[0]=(__bf16)a[0]; v[1]=(__bf16)a[1]; v[2]=(__bf16)a[2]; v[3]=(__bf16)a[3];
  v[4]=(__bf16)b[0]; v[5]=(__bf16)b[1]; v[6]=(__bf16)b[2]; v[7]=(__bf16)b[3];
  return v;
}
// async global->LDS, 16B/lane. PROPER addrspacecast (pointer cast, not the
// r1 integer round-trip which skipped the aperture conversion).
typedef __attribute__((address_space(1))) const void* as1cv;
typedef __attribute__((address_space(3))) void* as3v;
__device__ __forceinline__ void gld16(const u16* g, u16* l) {
  __builtin_amdgcn_global_load_lds((as1cv)g, (as3v)l, 16, 0, 0);
}

#define EPS 1.1920929e-07f

// ---------------------------------------------------------------------------
// cvt_pack: x (nx f32) + Wq|Wk|Wv|Wo (1M f32 each) -> bf16 blob
// dst layout: [xb nx][wqkv 3M][wo 1M]. 4 elems/thread/iter, 8B stores.
// ---------------------------------------------------------------------------
#define WSZ (1024 * 1024)
__global__ __launch_bounds__(256) void cvt_pack(
    const float* __restrict__ x, const float* __restrict__ wq,
    const float* __restrict__ wk, const float* __restrict__ wv,
    const float* __restrict__ wo, u16* __restrict__ dst, int nx)
{
  int idx4 = blockIdx.x * 256 + threadIdx.x;
  const int total4 = (nx + 4 * WSZ) >> 2;
  for (; idx4 < total4; idx4 += gridDim.x * 256) {
    int i = idx4 << 2;
    const float* src;
    if (i < nx) src = x + i;
    else {
      int o = i - nx;
      if      (o <     WSZ) src = wq + o;
      else if (o < 2 * WSZ) src = wk + o - WSZ;
      else if (o < 3 * WSZ) src = wv + o - 2 * WSZ;
      else                  src = wo + o - 3 * WSZ;
    }
    f32x4_t v = *(const f32x4*)src;
    u32x2_t p;
    p[0] = (u32)f2b(v[0]) | ((u32)f2b(v[1]) << 16);
    p[1] = (u32)f2b(v[2]) | ((u32)f2b(v[3]) << 16);
    *(u32x2*)(dst + i) = p;
  }
}

// ---------------------------------------------------------------------------
// gemm_bt2: C = A(MxK,bf16) @ B(NxK,bf16)^T + bias, m97 structure:
// 128x128 tile, BK=32, global_load_lds(16B) staging, 16x16x32 bf16 MFMA.
// NORM=1: fused RMSNorm over each 64-col head for segs 0,1 (q,k) — a wave's
// 64-col span is exactly one head; row-wise ss via 4 xor-shuffles (lanes of
// a quad share the output row). CF32: f32 C (d_out) vs bf16 ws.
// ---------------------------------------------------------------------------
#define BK 32
template<int NORM, int CF32>
__global__ __launch_bounds__(256, 2) void gemm_bt2(
    const u16* __restrict__ A, const u16* __restrict__ Bm,
    const float* __restrict__ bias0, const float* __restrict__ bias1, const float* __restrict__ bias2,
    const float* __restrict__ qn, const float* __restrict__ kn,
    void* __restrict__ C, int M, int K, int ldc)
{
  __shared__ alignas(16) u16 As[128 * BK];
  __shared__ alignas(16) u16 Bs[128 * BK];
  const int t = threadIdx.x;
  const int lane = t & 63, wave = t >> 6;
  const int quad = lane >> 4, col = lane & 15;
  const int m0 = blockIdx.x * 128, n0 = blockIdx.y * 128;
  const int seg = n0 >> 10, nl0 = n0 & 1023;
  const float* bias = seg == 0 ? bias0 : (seg == 1 ? bias1 : bias2);
  const int wm = (wave >> 1) * 64, wn = (wave & 1) * 64;

  const int lrow = t >> 2;
  const int lcol = (t & 3) * 8;
  const u16* ga0 = A  + (size_t)(m0 + lrow) * K + lcol;
  const u16* ga1 = A  + (size_t)(m0 + 64 + lrow) * K + lcol;
  const u16* gb0 = Bm + (size_t)(n0 + lrow) * K + lcol;
  const u16* gb1 = Bm + (size_t)(n0 + 64 + lrow) * K + lcol;
  u16* lA0 = As + t * 8;
  u16* lA1 = As + 64 * BK + t * 8;
  u16* lB0 = Bs + t * 8;
  u16* lB1 = Bs + 64 * BK + t * 8;

  f32x4_t acc[4][4] = {};
  for (int k0 = 0; k0 < K; k0 += BK) {
    __syncthreads();
    gld16(ga0 + k0, lA0);
    gld16(ga1 + k0, lA1);
    gld16(gb0 + k0, lB0);
    gld16(gb1 + k0, lB1);
    __syncthreads();
    bf16x8 af[4], bfr[4];
#pragma unroll
    for (int i = 0; i < 4; ++i) {
      af[i]  = *(const bf16x8*)(As + (wm + i * 16 + col) * BK + quad * 8);
      bfr[i] = *(const bf16x8*)(Bs + (wn + i * 16 + col) * BK + quad * 8);
    }
#pragma unroll
    for (int i = 0; i < 4; ++i)
#pragma unroll
      for (int j = 0; j < 4; ++j)
        acc[i][j] = __builtin_amdgcn_mfma_f32_16x16x32_bf16(af[i], bfr[j], acc[i][j], 0, 0, 0);
  }

  float bz[4], wz[4];
#pragma unroll
  for (int j = 0; j < 4; ++j) {
    bz[j] = bias[nl0 + wn + j * 16 + col];
    if (NORM) wz[j] = (seg == 0 ? qn : kn)[j * 16 + col];   // head dim j*16+col
  }
  const bool donorm = NORM && seg < 2;
#pragma unroll
  for (int i = 0; i < 4; ++i) {
#pragma unroll
    for (int rr = 0; rr < 4; ++rr) {
      int gm = m0 + wm + i * 16 + quad * 4 + rr;   // D row = quad*4+reg
      float v[4];
#pragma unroll
      for (int j = 0; j < 4; ++j) v[j] = acc[i][j][rr] + bz[j];
      if (donorm) {
        float ss = v[0]*v[0] + v[1]*v[1] + v[2]*v[2] + v[3]*v[3];
        ss += __shfl_xor(ss, 1);
        ss += __shfl_xor(ss, 2);
        ss += __shfl_xor(ss, 4);
        ss += __shfl_xor(ss, 8);
        float sc = rsqrtf(ss * (1.0f / 64.0f) + EPS);
#pragma unroll
        for (int j = 0; j < 4; ++j) v[j] *= sc * wz[j];
      }
      if (gm < M) {
#pragma unroll
        for (int j = 0; j < 4; ++j) {
          int gn = n0 + wn + j * 16 + col;
          if (CF32) ((float*)C)[(size_t)gm * ldc + gn] = v[j];
          else      ((u16*)C)[(size_t)gm * ldc + gn] = f2b(v[j]);
        }
      }
    }
  }
}

// ---------------------------------------------------------------------------
// FALLBACK tier kernels (r9, unchanged): cvt8-staging gemm + separate rmsnorm
// ---------------------------------------------------------------------------
template<int AF32, int CF32>
__global__ __launch_bounds__(256, 2) void gemm_bt(
    const void* __restrict__ Av,
    const float* __restrict__ B0, const float* __restrict__ B1, const float* __restrict__ B2,
    const float* __restrict__ bias0, const float* __restrict__ bias1, const float* __restrict__ bias2,
    void* __restrict__ C, int M, int K, int ldc)
{
  __shared__ alignas(16) u16 As[128 * BK];
  __shared__ alignas(16) u16 Bs[128 * BK];
  const int t = threadIdx.x;
  const int lane = t & 63, wave = t >> 6;
  const int quad = lane >> 4, col = lane & 15;
  const int m0 = blockIdx.x * 128, n0 = blockIdx.y * 128;
  const int seg = n0 >> 10;
  const float* B    = seg == 0 ? B0    : (seg == 1 ? B1    : B2);
  const float* bias = seg == 0 ? bias0 : (seg == 1 ? bias1 : bias2);
  const int nl0 = n0 & 1023;
  const int wm = (wave >> 1) * 64, wn = (wave & 1) * 64;
  const int lrow = t >> 2;
  const int lcol = (t & 3) * 8;
  int ar0 = m0 + lrow;      if (ar0 >= M) ar0 = M - 1;
  int ar1 = m0 + 64 + lrow; if (ar1 >= M) ar1 = M - 1;
  const float* bp0 = B + (size_t)(nl0 + lrow) * K + lcol;
  const float* bp1 = B + (size_t)(nl0 + 64 + lrow) * K + lcol;
  const float* apf0 = (const float*)Av + (size_t)ar0 * K + lcol;
  const float* apf1 = (const float*)Av + (size_t)ar1 * K + lcol;
  const u16*   aph0 = (const u16*)Av   + (size_t)ar0 * K + lcol;
  const u16*   aph1 = (const u16*)Av   + (size_t)ar1 * K + lcol;
  u16* lA0 = As + t * 8;
  u16* lA1 = As + 64 * BK + t * 8;
  u16* lB0 = Bs + t * 8;
  u16* lB1 = Bs + 64 * BK + t * 8;

  f32x4_t acc[4][4] = {};
  for (int k0 = 0; k0 < K; k0 += BK) {
    bf16x8_t va0, va1, vb0, vb1;
    if (AF32) { va0 = cvt8(apf0 + k0); va1 = cvt8(apf1 + k0); }
    else {
      u32x4_t r0 = *(const u32x4*)(aph0 + k0);
      u32x4_t r1 = *(const u32x4*)(aph1 + k0);
      __builtin_memcpy(&va0, &r0, 16);
      __builtin_memcpy(&va1, &r1, 16);
    }
    vb0 = cvt8(bp0 + k0);
    vb1 = cvt8(bp1 + k0);
    __syncthreads();
    *(bf16x8*)lA0 = va0; *(bf16x8*)lA1 = va1;
    *(bf16x8*)lB0 = vb0; *(bf16x8*)lB1 = vb1;
    __syncthreads();
    bf16x8 af[4], bfr[4];
#pragma unroll
    for (int i = 0; i < 4; ++i) {
      af[i]  = *(const bf16x8*)(As + (wm + i * 16 + col) * BK + quad * 8);
      bfr[i] = *(const bf16x8*)(Bs + (wn + i * 16 + col) * BK + quad * 8);
    }
#pragma unroll
    for (int i = 0; i < 4; ++i)
#pragma unroll
      for (int j = 0; j < 4; ++j)
        acc[i][j] = __builtin_amdgcn_mfma_f32_16x16x32_bf16(af[i], bfr[j], acc[i][j], 0, 0, 0);
  }
#pragma unroll
  for (int j = 0; j < 4; ++j) {
    int gn = n0 + wn + j * 16 + col;
    float bz = bias[nl0 + wn + j * 16 + col];
#pragma unroll
    for (int i = 0; i < 4; ++i) {
#pragma unroll
      for (int rr = 0; rr < 4; ++rr) {
        int gm = m0 + wm + i * 16 + quad * 4 + rr;
        if (gm < M) {
          float v = acc[i][j][rr] + bz;
          if (CF32) ((float*)C)[(size_t)gm * ldc + gn] = v;
          else      ((u16*)C)[(size_t)gm * ldc + gn] = f2b(v);
        }
      }
    }
  }
}

__global__ __launch_bounds__(256) void rmsnorm_qk(
    u16* __restrict__ qkv, const float* __restrict__ qn, const float* __restrict__ kn, int T)
{
  int gid = blockIdx.x * 256 + threadIdx.x;
  int row = gid >> 4, sub = gid & 15;
  if (row >= 2 * T * 16) return;
  int which = row >= T * 16;
  int r = which ? row - T * 16 : row;
  int tok = r >> 4, head = r & 15;
  u16* p = qkv + (size_t)tok * 3072 + which * 1024 + head * 64 + sub * 4;
  u16 d0 = p[0], d1 = p[1], d2 = p[2], d3 = p[3];
  float f0 = b2f(d0), f1 = b2f(d1), f2v = b2f(d2), f3 = b2f(d3);
  float ss = f0 * f0 + f1 * f1 + f2v * f2v + f3 * f3;
  ss += __shfl_xor(ss, 1);
  ss += __shfl_xor(ss, 2);
  ss += __shfl_xor(ss, 4);
  ss += __shfl_xor(ss, 8);
  float sc = rsqrtf(ss * (1.0f / 64.0f) + EPS);
  const float* w = which ? kn : qn;
  p[0] = f2b(f0 * sc * w[sub * 4 + 0]);
  p[1] = f2b(f1 * sc * w[sub * 4 + 1]);
  p[2] = f2b(f2v * sc * w[sub * 4 + 2]);
  p[3] = f2b(f3 * sc * w[sub * 4 + 3]);
}

// ---------------------------------------------------------------------------
// Flash attention (r9, unchanged): 64-key tiles, no-max softmax, l via
// ones-row MFMA, conflict-reduced strides.
// ---------------------------------------------------------------------------
#define SKS 68
#define SVS 66
#define SPS 68
__global__ __launch_bounds__(256, 2) void attn_fwd(
    const u16* __restrict__ qkv, const int* __restrict__ cu, u16* __restrict__ out)
{
  __shared__ alignas(16) u16 Ks[64 * SKS];
  __shared__ alignas(16) u16 Vts[80 * SVS];
  __shared__ alignas(16) u16 Ps[4 * 16 * SPS];
  const int seq = blockIdx.z, head = blockIdx.y, qt = blockIdx.x;
  const int start = cu[seq], len = cu[seq + 1] - start;
  const int q0 = qt * 64;
  if (q0 >= len) return;
  const int t = threadIdx.x;
  const int lane = t & 63, wave = t >> 6, quad = lane >> 4, col = lane & 15;

  {
    int rr = 64 + (t >> 4), ccol = (t & 15) * 4;
    u16 v = (t >> 4) == 0 ? (u16)0x3F80 : (u16)0;
    u16* p = Vts + rr * SVS + ccol;
    p[0] = v; p[1] = v; p[2] = v; p[3] = v;
  }

  int qrow = q0 + wave * 16 + col;
  int tq = start + (qrow < len ? qrow : len - 1);
  const u16* qp = qkv + (size_t)tq * 3072 + head * 64 + quad * 8;
  bf16x8 qf0 = *(const bf16x8*)qp;
  bf16x8 qf1 = *(const bf16x8*)(qp + 32);

  f32x4_t accO[4] = {};
  f32x4_t accL = {};
  const float SC = 0.125f * 1.44269504089f;

  const int kv = t >> 2, cc = t & 3;
  const int nkv = (len + 63) >> 6;
  for (int it = 0; it < nkv; ++it) {
    int k0 = it << 6;
    __syncthreads();
    {
      int tk = start + (k0 + kv < len ? k0 + kv : len - 1);
      const u16* kp = qkv + (size_t)tk * 3072 + 1024 + head * 64 + cc * 16;
      u32x4_t ka = *(const u32x4*)kp;
      u32x4_t kb2 = *(const u32x4*)(kp + 8);
      u32x4_t va = *(const u32x4*)(kp + 1024);
      u32x4_t vb = *(const u32x4*)(kp + 1032);
      *(u32x4*)(Ks + kv * SKS + cc * 16)     = ka;
      *(u32x4*)(Ks + kv * SKS + cc * 16 + 8) = kb2;
#pragma unroll
      for (int j = 0; j < 4; ++j) {
        u32 w = va[j];
        Vts[(cc*16 + 2*j    ) * SVS + kv] = (u16)(w & 0xffff);
        Vts[(cc*16 + 2*j + 1) * SVS + kv] = (u16)(w >> 16);
        u32 w2 = vb[j];
        Vts[(cc*16 + 8 + 2*j    ) * SVS + kv] = (u16)(w2 & 0xffff);
        Vts[(cc*16 + 8 + 2*j + 1) * SVS + kv] = (u16)(w2 >> 16);
      }
    }
    __syncthreads();

    f32x4_t sg[4];
#pragma unroll
    for (int g = 0; g < 4; ++g) {
      f32x4_t s = {};
      bf16x8 kb = *(const bf16x8*)(Ks + (g*16 + col) * SKS + quad * 8);
      s = __builtin_amdgcn_mfma_f32_16x16x32_bf16(qf0, kb, s, 0, 0, 0);
      kb = *(const bf16x8*)(Ks + (g*16 + col) * SKS + 32 + quad * 8);
      s = __builtin_amdgcn_mfma_f32_16x16x32_bf16(qf1, kb, s, 0, 0, 0);
      sg[g] = s;
    }

    const bool full = (k0 + 64 <= len);
    u16* pb = Ps + wave * (16 * SPS);
#pragma unroll
    for (int g = 0; g < 4; ++g) {
      bool vK = full || (k0 + g*16 + col) < len;
#pragma unroll
      for (int r = 0; r < 4; ++r) {
        float p = exp2f(sg[g][r] * SC);
        p = vK ? p : 0.0f;
        pb[(quad*4 + r) * SPS + g*16 + col] = f2b(p);
      }
    }
    __threadfence_block();

    bf16x8 pf0 = *(const bf16x8*)(pb + col * SPS + quad * 8);
    bf16x8 pf1 = *(const bf16x8*)(pb + col * SPS + 32 + quad * 8);
#pragma unroll
    for (int c = 0; c < 4; ++c) {
      bf16x8 vf = *(const bf16x8*)(Vts + (c*16 + col) * SVS + quad * 8);
      accO[c] = __builtin_amdgcn_mfma_f32_16x16x32_bf16(pf0, vf, accO[c], 0, 0, 0);
      vf = *(const bf16x8*)(Vts + (c*16 + col) * SVS + 32 + quad * 8);
      accO[c] = __builtin_amdgcn_mfma_f32_16x16x32_bf16(pf1, vf, accO[c], 0, 0, 0);
    }
    {
      bf16x8 of = *(const bf16x8*)(Vts + (64 + col) * SVS + quad * 8);
      accL = __builtin_amdgcn_mfma_f32_16x16x32_bf16(pf0, of, accL, 0, 0, 0);
      of = *(const bf16x8*)(Vts + (64 + col) * SVS + 32 + quad * 8);
      accL = __builtin_amdgcn_mfma_f32_16x16x32_bf16(pf1, of, accL, 0, 0, 0);
    }
  }

#pragma unroll
  for (int r = 0; r < 4; ++r) {
    int rowq = q0 + wave * 16 + quad * 4 + r;
    float l = __shfl(accL[r], lane & 48);
    if (rowq < len) {
      float inv = 1.0f / l;
      u16* op = out + (size_t)(start + rowq) * 1024 + head * 64 + col;
      op[0]  = f2b(accO[0][r] * inv);
      op[16] = f2b(accO[1][r] * inv);
      op[32] = f2b(accO[2][r] * inv);
      op[48] = f2b(accO[3][r] * inv);
    }
  }
}

__global__ void ws_too_small_sentinel(float* out) {
  if (threadIdx.x == 0 && blockIdx.x == 0) out[0] = 1024.0f;
}

// ---------------------------------------------------------------------------
extern "C" void kernel_launch(void* const* d_in, const int* in_sizes, int n_in,
                              void* d_out, int out_size, void* d_ws, size_t ws_size,
                              hipStream_t stream) {
  const float* x  = (const float*)d_in[0];
  const int*   cu = (const int*)d_in[1];
  const float* Wq = (const float*)d_in[2];
  const float* bq = (const float*)d_in[3];
  const float* Wk = (const float*)d_in[4];
  const float* bk = (const float*)d_in[5];
  const float* Wv = (const float*)d_in[6];
  const float* bv = (const float*)d_in[7];
  const float* qn = (const float*)d_in[8];
  const float* kn = (const float*)d_in[9];
  const float* Wo = (const float*)d_in[10];
  const float* bo = (const float*)d_in[11];

  const int T = in_sizes[0] / 1024;
  const int nseq = in_sizes[1] - 1;

  // ws layout (bf16): qkv T*3072 | attn T*1024 | xb T*1024 | wqkv 3M | wo 1M
  const size_t need_fast = ((size_t)T * 5120 + 4 * WSZ) * 2;   // 92.3 MB @ T=8192
  const size_t need_fall = (size_t)T * 4096 * 2;               // 67.1 MB

  u16* qkv  = (u16*)d_ws;
  u16* attn = qkv + (size_t)T * 3072;
  dim3 blk(256);

  if (ws_size >= need_fast) {
    u16* xb   = attn + (size_t)T * 1024;
    u16* wqkv = xb + (size_t)T * 1024;
    u16* wo   = wqkv + 3 * WSZ;
    // 1) convert inputs to bf16
    cvt_pack<<<dim3(1024), blk, 0, stream>>>(x, Wq, Wk, Wv, Wo, xb, T * 1024);
    // 2) fused QKV projection + RMSNorm epilogue (q,k segs)
    gemm_bt2<1, 0><<<dim3((T + 127) / 128, 24), blk, 0, stream>>>(
        xb, wqkv, bq, bk, bv, qn, kn, qkv, T, 1024, 3072);
    // 3) varlen MFMA flash attention
    attn_fwd<<<dim3(16, 16, nseq), blk, 0, stream>>>(qkv, cu, attn);
    // 4) output projection -> f32 d_out
    gemm_bt2<0, 1><<<dim3((T + 127) / 128, 8), blk, 0, stream>>>(
        attn, wo, bo, bo, bo, qn, kn, d_out, T, 1024, 1024);
  } else if (ws_size >= need_fall) {                 // r9 fallback path
    gemm_bt<1, 0><<<dim3((T + 127) / 128, 24), blk, 0, stream>>>(
        x, Wq, Wk, Wv, bq, bk, bv, qkv, T, 1024, 3072);
    rmsnorm_qk<<<dim3((2 * T * 256 + 255) / 256), blk, 0, stream>>>(qkv, qn, kn, T);
    attn_fwd<<<dim3(16, 16, nseq), blk, 0, stream>>>(qkv, cu, attn);
    gemm_bt<0, 1><<<dim3((T + 127) / 128, 8), blk, 0, stream>>>(
        attn, Wo, Wo, Wo, bo, bo, bo, d_out, T, 1024, 1024);
  } else {
    ws_too_small_sentinel<<<1, 64, 0, stream>>>((float*)d_out);
  }
}

// Round 11
// 311.011 us; speedup vs baseline: 33.7090x; 1.0255x over previous
//
#include <hip/hip_runtime.h>

typedef unsigned short u16;
typedef unsigned int   u32;

typedef __bf16 bf16x8_t __attribute__((ext_vector_type(8)));
typedef bf16x8_t bf16x8 __attribute__((may_alias));
typedef float f32x4_t __attribute__((ext_vector_type(4)));
typedef f32x4_t f32x4 __attribute__((may_alias));
typedef u32 u32x4_t __attribute__((ext_vector_type(4)));
typedef u32x4_t u32x4 __attribute__((may_alias));
typedef u32 u32x2_t __attribute__((ext_vector_type(2)));
typedef u32x2_t u32x2 __attribute__((may_alias));

__device__ __forceinline__ u16 f2b(float f) {        // RNE via hw cvt
  __bf16 h = (__bf16)f; u16 u; __builtin_memcpy(&u, &h, 2); return u;
}
__device__ __forceinline__ float b2f(u16 u) {
  u32 i = ((u32)u) << 16; float f; __builtin_memcpy(&f, &i, 4); return f;
}
__device__ __forceinline__ bf16x8_t cvt8(const float* p) {
  f32x4_t a = *(const f32x4*)p;
  f32x4_t b = *(const f32x4*)(p + 4);
  bf16x8_t v;
  v[0]=(__bf16)a[0]; v[1]=(__bf16)a[1]; v[2]=(__bf16)a[2]; v[3]=(__bf16)a[3];
  v[4]=(__bf16)b[0]; v[5]=(__bf16)b[1]; v[6]=(__bf16)b[2]; v[7]=(__bf16)b[3];
  return v;
}
// async global->LDS, 16B/lane (proper addrspacecast)
typedef __attribute__((address_space(1))) const void* as1cv;
typedef __attribute__((address_space(3))) void* as3v;
__device__ __forceinline__ void gld16(const u16* g, u16* l) {
  __builtin_amdgcn_global_load_lds((as1cv)g, (as3v)l, 16, 0, 0);
}

#define EPS 1.1920929e-07f

// ---------------------------------------------------------------------------
// cvt_pack: x (nx f32) + Wq|Wk|Wv|Wo (1M f32 each) -> bf16 blob (r10)
// ---------------------------------------------------------------------------
#define WSZ (1024 * 1024)
__global__ __launch_bounds__(256) void cvt_pack(
    const float* __restrict__ x, const float* __restrict__ wq,
    const float* __restrict__ wk, const float* __restrict__ wv,
    const float* __restrict__ wo, u16* __restrict__ dst, int nx)
{
  int idx4 = blockIdx.x * 256 + threadIdx.x;
  const int total4 = (nx + 4 * WSZ) >> 2;
  for (; idx4 < total4; idx4 += gridDim.x * 256) {
    int i = idx4 << 2;
    const float* src;
    if (i < nx) src = x + i;
    else {
      int o = i - nx;
      if      (o <     WSZ) src = wq + o;
      else if (o < 2 * WSZ) src = wk + o - WSZ;
      else if (o < 3 * WSZ) src = wv + o - 2 * WSZ;
      else                  src = wo + o - 3 * WSZ;
    }
    f32x4_t v = *(const f32x4*)src;
    u32x2_t p;
    p[0] = (u32)f2b(v[0]) | ((u32)f2b(v[1]) << 16);
    p[1] = (u32)f2b(v[2]) | ((u32)f2b(v[3]) << 16);
    *(u32x2*)(dst + i) = p;
  }
}

// ---------------------------------------------------------------------------
// gemm_bt2 (r10, unchanged): m97 structure + fused RMSNorm epilogue.
// ---------------------------------------------------------------------------
#define BK 32
template<int NORM, int CF32>
__global__ __launch_bounds__(256, 2) void gemm_bt2(
    const u16* __restrict__ A, const u16* __restrict__ Bm,
    const float* __restrict__ bias0, const float* __restrict__ bias1, const float* __restrict__ bias2,
    const float* __restrict__ qn, const float* __restrict__ kn,
    void* __restrict__ C, int M, int K, int ldc)
{
  __shared__ alignas(16) u16 As[128 * BK];
  __shared__ alignas(16) u16 Bs[128 * BK];
  const int t = threadIdx.x;
  const int lane = t & 63, wave = t >> 6;
  const int quad = lane >> 4, col = lane & 15;
  const int m0 = blockIdx.x * 128, n0 = blockIdx.y * 128;
  const int seg = n0 >> 10, nl0 = n0 & 1023;
  const float* bias = seg == 0 ? bias0 : (seg == 1 ? bias1 : bias2);
  const int wm = (wave >> 1) * 64, wn = (wave & 1) * 64;

  const int lrow = t >> 2;
  const int lcol = (t & 3) * 8;
  const u16* ga0 = A  + (size_t)(m0 + lrow) * K + lcol;
  const u16* ga1 = A  + (size_t)(m0 + 64 + lrow) * K + lcol;
  const u16* gb0 = Bm + (size_t)(n0 + lrow) * K + lcol;
  const u16* gb1 = Bm + (size_t)(n0 + 64 + lrow) * K + lcol;
  u16* lA0 = As + t * 8;
  u16* lA1 = As + 64 * BK + t * 8;
  u16* lB0 = Bs + t * 8;
  u16* lB1 = Bs + 64 * BK + t * 8;

  f32x4_t acc[4][4] = {};
  for (int k0 = 0; k0 < K; k0 += BK) {
    __syncthreads();
    gld16(ga0 + k0, lA0);
    gld16(ga1 + k0, lA1);
    gld16(gb0 + k0, lB0);
    gld16(gb1 + k0, lB1);
    __syncthreads();
    bf16x8 af[4], bfr[4];
#pragma unroll
    for (int i = 0; i < 4; ++i) {
      af[i]  = *(const bf16x8*)(As + (wm + i * 16 + col) * BK + quad * 8);
      bfr[i] = *(const bf16x8*)(Bs + (wn + i * 16 + col) * BK + quad * 8);
    }
#pragma unroll
    for (int i = 0; i < 4; ++i)
#pragma unroll
      for (int j = 0; j < 4; ++j)
        acc[i][j] = __builtin_amdgcn_mfma_f32_16x16x32_bf16(af[i], bfr[j], acc[i][j], 0, 0, 0);
  }

  float bz[4], wz[4];
#pragma unroll
  for (int j = 0; j < 4; ++j) {
    bz[j] = bias[nl0 + wn + j * 16 + col];
    if (NORM) wz[j] = (seg == 0 ? qn : kn)[j * 16 + col];
  }
  const bool donorm = NORM && seg < 2;
#pragma unroll
  for (int i = 0; i < 4; ++i) {
#pragma unroll
    for (int rr = 0; rr < 4; ++rr) {
      int gm = m0 + wm + i * 16 + quad * 4 + rr;
      float v[4];
#pragma unroll
      for (int j = 0; j < 4; ++j) v[j] = acc[i][j][rr] + bz[j];
      if (donorm) {
        float ss = v[0]*v[0] + v[1]*v[1] + v[2]*v[2] + v[3]*v[3];
        ss += __shfl_xor(ss, 1);
        ss += __shfl_xor(ss, 2);
        ss += __shfl_xor(ss, 4);
        ss += __shfl_xor(ss, 8);
        float sc = rsqrtf(ss * (1.0f / 64.0f) + EPS);
#pragma unroll
        for (int j = 0; j < 4; ++j) v[j] *= sc * wz[j];
      }
      if (gm < M) {
#pragma unroll
        for (int j = 0; j < 4; ++j) {
          int gn = n0 + wn + j * 16 + col;
          if (CF32) ((float*)C)[(size_t)gm * ldc + gn] = v[j];
          else      ((u16*)C)[(size_t)gm * ldc + gn] = f2b(v[j]);
        }
      }
    }
  }
}

// ---------------------------------------------------------------------------
// FALLBACK tier kernels (r9, unchanged)
// ---------------------------------------------------------------------------
template<int AF32, int CF32>
__global__ __launch_bounds__(256, 2) void gemm_bt(
    const void* __restrict__ Av,
    const float* __restrict__ B0, const float* __restrict__ B1, const float* __restrict__ B2,
    const float* __restrict__ bias0, const float* __restrict__ bias1, const float* __restrict__ bias2,
    void* __restrict__ C, int M, int K, int ldc)
{
  __shared__ alignas(16) u16 As[128 * BK];
  __shared__ alignas(16) u16 Bs[128 * BK];
  const int t = threadIdx.x;
  const int lane = t & 63, wave = t >> 6;
  const int quad = lane >> 4, col = lane & 15;
  const int m0 = blockIdx.x * 128, n0 = blockIdx.y * 128;
  const int seg = n0 >> 10;
  const float* B    = seg == 0 ? B0    : (seg == 1 ? B1    : B2);
  const float* bias = seg == 0 ? bias0 : (seg == 1 ? bias1 : bias2);
  const int nl0 = n0 & 1023;
  const int wm = (wave >> 1) * 64, wn = (wave & 1) * 64;
  const int lrow = t >> 2;
  const int lcol = (t & 3) * 8;
  int ar0 = m0 + lrow;      if (ar0 >= M) ar0 = M - 1;
  int ar1 = m0 + 64 + lrow; if (ar1 >= M) ar1 = M - 1;
  const float* bp0 = B + (size_t)(nl0 + lrow) * K + lcol;
  const float* bp1 = B + (size_t)(nl0 + 64 + lrow) * K + lcol;
  const float* apf0 = (const float*)Av + (size_t)ar0 * K + lcol;
  const float* apf1 = (const float*)Av + (size_t)ar1 * K + lcol;
  const u16*   aph0 = (const u16*)Av   + (size_t)ar0 * K + lcol;
  const u16*   aph1 = (const u16*)Av   + (size_t)ar1 * K + lcol;
  u16* lA0 = As + t * 8;
  u16* lA1 = As + 64 * BK + t * 8;
  u16* lB0 = Bs + t * 8;
  u16* lB1 = Bs + 64 * BK + t * 8;

  f32x4_t acc[4][4] = {};
  for (int k0 = 0; k0 < K; k0 += BK) {
    bf16x8_t va0, va1, vb0, vb1;
    if (AF32) { va0 = cvt8(apf0 + k0); va1 = cvt8(apf1 + k0); }
    else {
      u32x4_t r0 = *(const u32x4*)(aph0 + k0);
      u32x4_t r1 = *(const u32x4*)(aph1 + k0);
      __builtin_memcpy(&va0, &r0, 16);
      __builtin_memcpy(&va1, &r1, 16);
    }
    vb0 = cvt8(bp0 + k0);
    vb1 = cvt8(bp1 + k0);
    __syncthreads();
    *(bf16x8*)lA0 = va0; *(bf16x8*)lA1 = va1;
    *(bf16x8*)lB0 = vb0; *(bf16x8*)lB1 = vb1;
    __syncthreads();
    bf16x8 af[4], bfr[4];
#pragma unroll
    for (int i = 0; i < 4; ++i) {
      af[i]  = *(const bf16x8*)(As + (wm + i * 16 + col) * BK + quad * 8);
      bfr[i] = *(const bf16x8*)(Bs + (wn + i * 16 + col) * BK + quad * 8);
    }
#pragma unroll
    for (int i = 0; i < 4; ++i)
#pragma unroll
      for (int j = 0; j < 4; ++j)
        acc[i][j] = __builtin_amdgcn_mfma_f32_16x16x32_bf16(af[i], bfr[j], acc[i][j], 0, 0, 0);
  }
#pragma unroll
  for (int j = 0; j < 4; ++j) {
    int gn = n0 + wn + j * 16 + col;
    float bz = bias[nl0 + wn + j * 16 + col];
#pragma unroll
    for (int i = 0; i < 4; ++i) {
#pragma unroll
      for (int rr = 0; rr < 4; ++rr) {
        int gm = m0 + wm + i * 16 + quad * 4 + rr;
        if (gm < M) {
          float v = acc[i][j][rr] + bz;
          if (CF32) ((float*)C)[(size_t)gm * ldc + gn] = v;
          else      ((u16*)C)[(size_t)gm * ldc + gn] = f2b(v);
        }
      }
    }
  }
}

__global__ __launch_bounds__(256) void rmsnorm_qk(
    u16* __restrict__ qkv, const float* __restrict__ qn, const float* __restrict__ kn, int T)
{
  int gid = blockIdx.x * 256 + threadIdx.x;
  int row = gid >> 4, sub = gid & 15;
  if (row >= 2 * T * 16) return;
  int which = row >= T * 16;
  int r = which ? row - T * 16 : row;
  int tok = r >> 4, head = r & 15;
  u16* p = qkv + (size_t)tok * 3072 + which * 1024 + head * 64 + sub * 4;
  u16 d0 = p[0], d1 = p[1], d2 = p[2], d3 = p[3];
  float f0 = b2f(d0), f1 = b2f(d1), f2v = b2f(d2), f3 = b2f(d3);
  float ss = f0 * f0 + f1 * f1 + f2v * f2v + f3 * f3;
  ss += __shfl_xor(ss, 1);
  ss += __shfl_xor(ss, 2);
  ss += __shfl_xor(ss, 4);
  ss += __shfl_xor(ss, 8);
  float sc = rsqrtf(ss * (1.0f / 64.0f) + EPS);
  const float* w = which ? kn : qn;
  p[0] = f2b(f0 * sc * w[sub * 4 + 0]);
  p[1] = f2b(f1 * sc * w[sub * 4 + 1]);
  p[2] = f2b(f2v * sc * w[sub * 4 + 2]);
  p[3] = f2b(f3 * sc * w[sub * 4 + 3]);
}

// ---------------------------------------------------------------------------
// Flash attention v3: register-prefetch pipeline + key-permuted P/V layouts.
// Key permutation k' = (k&15)*4 + (k>>4), applied identically to P columns
// and V^T columns (PV sums over k: any consistent permutation is exact).
//  - P write: thread's 4 values (keys g*16+col) -> [row][col*4+g] = 1 b64/row
//  - V stage: thread handles keys (c+32h, c+16+32h): their k' are adjacent
//    -> 8 packed b32 writes instead of 16 scattered b16
//  - all strides 68 u16 (34 dw): every b128 read is 2-way (free, m136)
//  - prefetch tile it+1 into VGPRs during compute of tile it
// ---------------------------------------------------------------------------
#define SKS 68
#define SVS 68
#define SPS 68
__global__ __launch_bounds__(256, 2) void attn_fwd(
    const u16* __restrict__ qkv, const int* __restrict__ cu, u16* __restrict__ out)
{
  __shared__ alignas(16) u16 Ks[64 * SKS];
  __shared__ alignas(16) u16 Vts[66 * SVS];     // rows 0..63 dims, row 64 = ones
  __shared__ alignas(16) u16 Ps[4 * 16 * SPS];
  const int seq = blockIdx.z, head = blockIdx.y, qt = blockIdx.x;
  const int start = cu[seq], len = cu[seq + 1] - start;
  const int q0 = qt * 64;
  if (q0 >= len) return;
  const int t = threadIdx.x;
  const int lane = t & 63, wave = t >> 6, quad = lane >> 4, col = lane & 15;

  if (t < 64) Vts[64 * SVS + t] = 0x3F80;       // ones row (bf16 1.0)

  int qrow = q0 + wave * 16 + col;
  int tq = start + (qrow < len ? qrow : len - 1);
  const u16* qp = qkv + (size_t)tq * 3072 + head * 64 + quad * 8;
  bf16x8 qf0 = *(const bf16x8*)qp;
  bf16x8 qf1 = *(const bf16x8*)(qp + 32);

  f32x4_t accO[4] = {};
  f32x4_t accL = {};
  const float SC = 0.125f * 1.44269504089f;

  // staging: sp = t>>3 encodes (kc = sp&15, kh = sp>>4); dc = t&7 (8-dim chunk)
  const int sp = t >> 3, dc = t & 7;
  const int kc = sp & 15, kh = sp >> 4;
  const int keyA = kc + 32 * kh;                 // pair: keyA, keyA+16
  u16* ksA = Ks + keyA * SKS + dc * 8;
  u16* ksB = Ks + (keyA + 16) * SKS + dc * 8;
  const int vcol = kc * 4 + 2 * kh;              // k'(keyA); k'(keyA+16)=vcol+1
  const size_t kvbase = 1024 + head * 64 + dc * 8;

  const int nkv = (len + 63) >> 6;
  u32x4_t rkA, rkB, rvA, rvB;
  {   // prologue: load tile 0
    int ta = start + (keyA      < len ? keyA      : len - 1);
    int tb = start + (keyA + 16 < len ? keyA + 16 : len - 1);
    const u16* pa = qkv + (size_t)ta * 3072 + kvbase;
    const u16* pb2 = qkv + (size_t)tb * 3072 + kvbase;
    rkA = *(const u32x4*)pa;   rvA = *(const u32x4*)(pa + 1024);
    rkB = *(const u32x4*)pb2;  rvB = *(const u32x4*)(pb2 + 1024);
  }

  for (int it = 0; it < nkv; ++it) {
    const int k0 = it << 6;
    __syncthreads();                             // prior compute done with LDS
    *(u32x4*)ksA = rkA;
    *(u32x4*)ksB = rkB;
    {
      const u16* a = (const u16*)&rvA;
      const u16* b = (const u16*)&rvB;
#pragma unroll
      for (int j = 0; j < 8; ++j) {              // V^T packed pair writes
        u32 pk = (u32)a[j] | ((u32)b[j] << 16);
        *(u32*)(Vts + (dc * 8 + j) * SVS + vcol) = pk;
      }
    }
    __syncthreads();
    if (it + 1 < nkv) {                          // prefetch next tile -> regs
      int kb0 = k0 + 64;
      int ta = start + (kb0 + keyA      < len ? kb0 + keyA      : len - 1);
      int tb = start + (kb0 + keyA + 16 < len ? kb0 + keyA + 16 : len - 1);
      const u16* pa = qkv + (size_t)ta * 3072 + kvbase;
      const u16* pb2 = qkv + (size_t)tb * 3072 + kvbase;
      rkA = *(const u32x4*)pa;   rvA = *(const u32x4*)(pa + 1024);
      rkB = *(const u32x4*)pb2;  rvB = *(const u32x4*)(pb2 + 1024);
    }

    // S = Q.K^T (keys in natural order)
    f32x4_t sg[4];
#pragma unroll
    for (int g = 0; g < 4; ++g) {
      f32x4_t s = {};
      bf16x8 kb = *(const bf16x8*)(Ks + (g*16 + col) * SKS + quad * 8);
      s = __builtin_amdgcn_mfma_f32_16x16x32_bf16(qf0, kb, s, 0, 0, 0);
      kb = *(const bf16x8*)(Ks + (g*16 + col) * SKS + 32 + quad * 8);
      s = __builtin_amdgcn_mfma_f32_16x16x32_bf16(qf1, kb, s, 0, 0, 0);
      sg[g] = s;
    }

    // P = exp2(S*SC) masked; key g*16+col -> column col*4+g (b64 per row)
    const bool full = (k0 + 64 <= len);
    u16* pbw = Ps + wave * (16 * SPS);
    bool vg[4];
#pragma unroll
    for (int g = 0; g < 4; ++g) vg[g] = full || (k0 + g*16 + col) < len;
#pragma unroll
    for (int r = 0; r < 4; ++r) {
      u16 pe[4];
#pragma unroll
      for (int g = 0; g < 4; ++g) {
        float p = exp2f(sg[g][r] * SC);
        pe[g] = vg[g] ? f2b(p) : (u16)0;
      }
      u32x2_t w;
      w[0] = (u32)pe[0] | ((u32)pe[1] << 16);
      w[1] = (u32)pe[2] | ((u32)pe[3] << 16);
      *(u32x2*)(pbw + (quad*4 + r) * SPS + col * 4) = w;
    }
    __threadfence_block();

    bf16x8 pf0 = *(const bf16x8*)(pbw + col * SPS + quad * 8);       // k' 0..31
    bf16x8 pf1 = *(const bf16x8*)(pbw + col * SPS + 32 + quad * 8);  // k' 32..63
#pragma unroll
    for (int c = 0; c < 4; ++c) {
      bf16x8 vf = *(const bf16x8*)(Vts + (c*16 + col) * SVS + quad * 8);
      accO[c] = __builtin_amdgcn_mfma_f32_16x16x32_bf16(pf0, vf, accO[c], 0, 0, 0);
      vf = *(const bf16x8*)(Vts + (c*16 + col) * SVS + 32 + quad * 8);
      accO[c] = __builtin_amdgcn_mfma_f32_16x16x32_bf16(pf1, vf, accO[c], 0, 0, 0);
    }
    {
      bf16x8 of = *(const bf16x8*)(Vts + 64 * SVS + quad * 8);
      accL = __builtin_amdgcn_mfma_f32_16x16x32_bf16(pf0, of, accL, 0, 0, 0);
      of = *(const bf16x8*)(Vts + 64 * SVS + 32 + quad * 8);
      accL = __builtin_amdgcn_mfma_f32_16x16x32_bf16(pf1, of, accL, 0, 0, 0);
    }
  }

#pragma unroll
  for (int r = 0; r < 4; ++r) {
    int rowq = q0 + wave * 16 + quad * 4 + r;
    float l = __shfl(accL[r], lane & 48);
    if (rowq < len) {
      float inv = 1.0f / l;
      u16* op = out + (size_t)(start + rowq) * 1024 + head * 64 + col;
      op[0]  = f2b(accO[0][r] * inv);
      op[16] = f2b(accO[1][r] * inv);
      op[32] = f2b(accO[2][r] * inv);
      op[48] = f2b(accO[3][r] * inv);
    }
  }
}

__global__ void ws_too_small_sentinel(float* out) {
  if (threadIdx.x == 0 && blockIdx.x == 0) out[0] = 1024.0f;
}

// ---------------------------------------------------------------------------
extern "C" void kernel_launch(void* const* d_in, const int* in_sizes, int n_in,
                              void* d_out, int out_size, void* d_ws, size_t ws_size,
                              hipStream_t stream) {
  const float* x  = (const float*)d_in[0];
  const int*   cu = (const int*)d_in[1];
  const float* Wq = (const float*)d_in[2];
  const float* bq = (const float*)d_in[3];
  const float* Wk = (const float*)d_in[4];
  const float* bk = (const float*)d_in[5];
  const float* Wv = (const float*)d_in[6];
  const float* bv = (const float*)d_in[7];
  const float* qn = (const float*)d_in[8];
  const float* kn = (const float*)d_in[9];
  const float* Wo = (const float*)d_in[10];
  const float* bo = (const float*)d_in[11];

  const int T = in_sizes[0] / 1024;
  const int nseq = in_sizes[1] - 1;

  const size_t need_fast = ((size_t)T * 5120 + 4 * WSZ) * 2;   // 92.3 MB @ T=8192
  const size_t need_fall = (size_t)T * 4096 * 2;               // 67.1 MB

  u16* qkv  = (u16*)d_ws;
  u16* attn = qkv + (size_t)T * 3072;
  dim3 blk(256);

  if (ws_size >= need_fast) {
    u16* xb   = attn + (size_t)T * 1024;
    u16* wqkv = xb + (size_t)T * 1024;
    u16* wo   = wqkv + 3 * WSZ;
    cvt_pack<<<dim3(1024), blk, 0, stream>>>(x, Wq, Wk, Wv, Wo, xb, T * 1024);
    gemm_bt2<1, 0><<<dim3((T + 127) / 128, 24), blk, 0, stream>>>(
        xb, wqkv, bq, bk, bv, qn, kn, qkv, T, 1024, 3072);
    attn_fwd<<<dim3(16, 16, nseq), blk, 0, stream>>>(qkv, cu, attn);
    gemm_bt2<0, 1><<<dim3((T + 127) / 128, 8), blk, 0, stream>>>(
        attn, wo, bo, bo, bo, qn, kn, d_out, T, 1024, 1024);
  } else if (ws_size >= need_fall) {
    gemm_bt<1, 0><<<dim3((T + 127) / 128, 24), blk, 0, stream>>>(
        x, Wq, Wk, Wv, bq, bk, bv, qkv, T, 1024, 3072);
    rmsnorm_qk<<<dim3((2 * T * 256 + 255) / 256), blk, 0, stream>>>(qkv, qn, kn, T);
    attn_fwd<<<dim3(16, 16, nseq), blk, 0, stream>>>(qkv, cu, attn);
    gemm_bt<0, 1><<<dim3((T + 127) / 128, 8), blk, 0, stream>>>(
        attn, Wo, Wo, Wo, bo, bo, bo, d_out, T, 1024, 1024);
  } else {
    ws_too_small_sentinel<<<1, 64, 0, stream>>>((float*)d_out);
  }
}

// Round 12
// 291.265 us; speedup vs baseline: 35.9943x; 1.0678x over previous
//
#include <hip/hip_runtime.h>

typedef unsigned short u16;
typedef unsigned int   u32;

typedef __bf16 bf16x8_t __attribute__((ext_vector_type(8)));
typedef bf16x8_t bf16x8 __attribute__((may_alias));
typedef float f32x4_t __attribute__((ext_vector_type(4)));
typedef f32x4_t f32x4 __attribute__((may_alias));
typedef u32 u32x4_t __attribute__((ext_vector_type(4)));
typedef u32x4_t u32x4 __attribute__((may_alias));
typedef u32 u32x2_t __attribute__((ext_vector_type(2)));
typedef u32x2_t u32x2 __attribute__((may_alias));

__device__ __forceinline__ u16 f2b(float f) {        // RNE via hw cvt
  __bf16 h = (__bf16)f; u16 u; __builtin_memcpy(&u, &h, 2); return u;
}
__device__ __forceinline__ float b2f(u16 u) {
  u32 i = ((u32)u) << 16; float f; __builtin_memcpy(&f, &i, 4); return f;
}
__device__ __forceinline__ bf16x8_t cvt8(const float* p) {
  f32x4_t a = *(const f32x4*)p;
  f32x4_t b = *(const f32x4*)(p + 4);
  bf16x8_t v;
  v[0]=(__bf16)a[0]; v[1]=(__bf16)a[1]; v[2]=(__bf16)a[2]; v[3]=(__bf16)a[3];
  v[4]=(__bf16)b[0]; v[5]=(__bf16)b[1]; v[6]=(__bf16)b[2]; v[7]=(__bf16)b[3];
  return v;
}
// async global->LDS, 16B/lane (proper addrspacecast)
typedef __attribute__((address_space(1))) const void* as1cv;
typedef __attribute__((address_space(3))) void* as3v;
__device__ __forceinline__ void gld16(const u16* g, u16* l) {
  __builtin_amdgcn_global_load_lds((as1cv)g, (as3v)l, 16, 0, 0);
}

#define EPS 1.1920929e-07f

// ---------------------------------------------------------------------------
// cvt_pack: x (nx f32) + Wq|Wk|Wv|Wo (1M f32 each) -> bf16 blob (r10)
// ---------------------------------------------------------------------------
#define WSZ (1024 * 1024)
__global__ __launch_bounds__(256) void cvt_pack(
    const float* __restrict__ x, const float* __restrict__ wq,
    const float* __restrict__ wk, const float* __restrict__ wv,
    const float* __restrict__ wo, u16* __restrict__ dst, int nx)
{
  int idx4 = blockIdx.x * 256 + threadIdx.x;
  const int total4 = (nx + 4 * WSZ) >> 2;
  for (; idx4 < total4; idx4 += gridDim.x * 256) {
    int i = idx4 << 2;
    const float* src;
    if (i < nx) src = x + i;
    else {
      int o = i - nx;
      if      (o <     WSZ) src = wq + o;
      else if (o < 2 * WSZ) src = wk + o - WSZ;
      else if (o < 3 * WSZ) src = wv + o - 2 * WSZ;
      else                  src = wo + o - 3 * WSZ;
    }
    f32x4_t v = *(const f32x4*)src;
    u32x2_t p;
    p[0] = (u32)f2b(v[0]) | ((u32)f2b(v[1]) << 16);
    p[1] = (u32)f2b(v[2]) | ((u32)f2b(v[3]) << 16);
    *(u32x2*)(dst + i) = p;
  }
}

// ---------------------------------------------------------------------------
// gemm_bt2 (r10, unchanged): m97 structure + fused RMSNorm epilogue.
// ---------------------------------------------------------------------------
#define BK 32
template<int NORM, int CF32>
__global__ __launch_bounds__(256, 2) void gemm_bt2(
    const u16* __restrict__ A, const u16* __restrict__ Bm,
    const float* __restrict__ bias0, const float* __restrict__ bias1, const float* __restrict__ bias2,
    const float* __restrict__ qn, const float* __restrict__ kn,
    void* __restrict__ C, int M, int K, int ldc)
{
  __shared__ alignas(16) u16 As[128 * BK];
  __shared__ alignas(16) u16 Bs[128 * BK];
  const int t = threadIdx.x;
  const int lane = t & 63, wave = t >> 6;
  const int quad = lane >> 4, col = lane & 15;
  const int m0 = blockIdx.x * 128, n0 = blockIdx.y * 128;
  const int seg = n0 >> 10, nl0 = n0 & 1023;
  const float* bias = seg == 0 ? bias0 : (seg == 1 ? bias1 : bias2);
  const int wm = (wave >> 1) * 64, wn = (wave & 1) * 64;

  const int lrow = t >> 2;
  const int lcol = (t & 3) * 8;
  const u16* ga0 = A  + (size_t)(m0 + lrow) * K + lcol;
  const u16* ga1 = A  + (size_t)(m0 + 64 + lrow) * K + lcol;
  const u16* gb0 = Bm + (size_t)(n0 + lrow) * K + lcol;
  const u16* gb1 = Bm + (size_t)(n0 + 64 + lrow) * K + lcol;
  u16* lA0 = As + t * 8;
  u16* lA1 = As + 64 * BK + t * 8;
  u16* lB0 = Bs + t * 8;
  u16* lB1 = Bs + 64 * BK + t * 8;

  f32x4_t acc[4][4] = {};
  for (int k0 = 0; k0 < K; k0 += BK) {
    __syncthreads();
    gld16(ga0 + k0, lA0);
    gld16(ga1 + k0, lA1);
    gld16(gb0 + k0, lB0);
    gld16(gb1 + k0, lB1);
    __syncthreads();
    bf16x8 af[4], bfr[4];
#pragma unroll
    for (int i = 0; i < 4; ++i) {
      af[i]  = *(const bf16x8*)(As + (wm + i * 16 + col) * BK + quad * 8);
      bfr[i] = *(const bf16x8*)(Bs + (wn + i * 16 + col) * BK + quad * 8);
    }
#pragma unroll
    for (int i = 0; i < 4; ++i)
#pragma unroll
      for (int j = 0; j < 4; ++j)
        acc[i][j] = __builtin_amdgcn_mfma_f32_16x16x32_bf16(af[i], bfr[j], acc[i][j], 0, 0, 0);
  }

  float bz[4], wz[4];
#pragma unroll
  for (int j = 0; j < 4; ++j) {
    bz[j] = bias[nl0 + wn + j * 16 + col];
    if (NORM) wz[j] = (seg == 0 ? qn : kn)[j * 16 + col];
  }
  const bool donorm = NORM && seg < 2;
#pragma unroll
  for (int i = 0; i < 4; ++i) {
#pragma unroll
    for (int rr = 0; rr < 4; ++rr) {
      int gm = m0 + wm + i * 16 + quad * 4 + rr;
      float v[4];
#pragma unroll
      for (int j = 0; j < 4; ++j) v[j] = acc[i][j][rr] + bz[j];
      if (donorm) {
        float ss = v[0]*v[0] + v[1]*v[1] + v[2]*v[2] + v[3]*v[3];
        ss += __shfl_xor(ss, 1);
        ss += __shfl_xor(ss, 2);
        ss += __shfl_xor(ss, 4);
        ss += __shfl_xor(ss, 8);
        float sc = rsqrtf(ss * (1.0f / 64.0f) + EPS);
#pragma unroll
        for (int j = 0; j < 4; ++j) v[j] *= sc * wz[j];
      }
      if (gm < M) {
#pragma unroll
        for (int j = 0; j < 4; ++j) {
          int gn = n0 + wn + j * 16 + col;
          if (CF32) ((float*)C)[(size_t)gm * ldc + gn] = v[j];
          else      ((u16*)C)[(size_t)gm * ldc + gn] = f2b(v[j]);
        }
      }
    }
  }
}

// ---------------------------------------------------------------------------
// FALLBACK tier kernels (r9, unchanged)
// ---------------------------------------------------------------------------
template<int AF32, int CF32>
__global__ __launch_bounds__(256, 2) void gemm_bt(
    const void* __restrict__ Av,
    const float* __restrict__ B0, const float* __restrict__ B1, const float* __restrict__ B2,
    const float* __restrict__ bias0, const float* __restrict__ bias1, const float* __restrict__ bias2,
    void* __restrict__ C, int M, int K, int ldc)
{
  __shared__ alignas(16) u16 As[128 * BK];
  __shared__ alignas(16) u16 Bs[128 * BK];
  const int t = threadIdx.x;
  const int lane = t & 63, wave = t >> 6;
  const int quad = lane >> 4, col = lane & 15;
  const int m0 = blockIdx.x * 128, n0 = blockIdx.y * 128;
  const int seg = n0 >> 10;
  const float* B    = seg == 0 ? B0    : (seg == 1 ? B1    : B2);
  const float* bias = seg == 0 ? bias0 : (seg == 1 ? bias1 : bias2);
  const int nl0 = n0 & 1023;
  const int wm = (wave >> 1) * 64, wn = (wave & 1) * 64;
  const int lrow = t >> 2;
  const int lcol = (t & 3) * 8;
  int ar0 = m0 + lrow;      if (ar0 >= M) ar0 = M - 1;
  int ar1 = m0 + 64 + lrow; if (ar1 >= M) ar1 = M - 1;
  const float* bp0 = B + (size_t)(nl0 + lrow) * K + lcol;
  const float* bp1 = B + (size_t)(nl0 + 64 + lrow) * K + lcol;
  const float* apf0 = (const float*)Av + (size_t)ar0 * K + lcol;
  const float* apf1 = (const float*)Av + (size_t)ar1 * K + lcol;
  const u16*   aph0 = (const u16*)Av   + (size_t)ar0 * K + lcol;
  const u16*   aph1 = (const u16*)Av   + (size_t)ar1 * K + lcol;
  u16* lA0 = As + t * 8;
  u16* lA1 = As + 64 * BK + t * 8;
  u16* lB0 = Bs + t * 8;
  u16* lB1 = Bs + 64 * BK + t * 8;

  f32x4_t acc[4][4] = {};
  for (int k0 = 0; k0 < K; k0 += BK) {
    bf16x8_t va0, va1, vb0, vb1;
    if (AF32) { va0 = cvt8(apf0 + k0); va1 = cvt8(apf1 + k0); }
    else {
      u32x4_t r0 = *(const u32x4*)(aph0 + k0);
      u32x4_t r1 = *(const u32x4*)(aph1 + k0);
      __builtin_memcpy(&va0, &r0, 16);
      __builtin_memcpy(&va1, &r1, 16);
    }
    vb0 = cvt8(bp0 + k0);
    vb1 = cvt8(bp1 + k0);
    __syncthreads();
    *(bf16x8*)lA0 = va0; *(bf16x8*)lA1 = va1;
    *(bf16x8*)lB0 = vb0; *(bf16x8*)lB1 = vb1;
    __syncthreads();
    bf16x8 af[4], bfr[4];
#pragma unroll
    for (int i = 0; i < 4; ++i) {
      af[i]  = *(const bf16x8*)(As + (wm + i * 16 + col) * BK + quad * 8);
      bfr[i] = *(const bf16x8*)(Bs + (wn + i * 16 + col) * BK + quad * 8);
    }
#pragma unroll
    for (int i = 0; i < 4; ++i)
#pragma unroll
      for (int j = 0; j < 4; ++j)
        acc[i][j] = __builtin_amdgcn_mfma_f32_16x16x32_bf16(af[i], bfr[j], acc[i][j], 0, 0, 0);
  }
#pragma unroll
  for (int j = 0; j < 4; ++j) {
    int gn = n0 + wn + j * 16 + col;
    float bz = bias[nl0 + wn + j * 16 + col];
#pragma unroll
    for (int i = 0; i < 4; ++i) {
#pragma unroll
      for (int rr = 0; rr < 4; ++rr) {
        int gm = m0 + wm + i * 16 + quad * 4 + rr;
        if (gm < M) {
          float v = acc[i][j][rr] + bz;
          if (CF32) ((float*)C)[(size_t)gm * ldc + gn] = v;
          else      ((u16*)C)[(size_t)gm * ldc + gn] = f2b(v);
        }
      }
    }
  }
}

__global__ __launch_bounds__(256) void rmsnorm_qk(
    u16* __restrict__ qkv, const float* __restrict__ qn, const float* __restrict__ kn, int T)
{
  int gid = blockIdx.x * 256 + threadIdx.x;
  int row = gid >> 4, sub = gid & 15;
  if (row >= 2 * T * 16) return;
  int which = row >= T * 16;
  int r = which ? row - T * 16 : row;
  int tok = r >> 4, head = r & 15;
  u16* p = qkv + (size_t)tok * 3072 + which * 1024 + head * 64 + sub * 4;
  u16 d0 = p[0], d1 = p[1], d2 = p[2], d3 = p[3];
  float f0 = b2f(d0), f1 = b2f(d1), f2v = b2f(d2), f3 = b2f(d3);
  float ss = f0 * f0 + f1 * f1 + f2v * f2v + f3 * f3;
  ss += __shfl_xor(ss, 1);
  ss += __shfl_xor(ss, 2);
  ss += __shfl_xor(ss, 4);
  ss += __shfl_xor(ss, 8);
  float sc = rsqrtf(ss * (1.0f / 64.0f) + EPS);
  const float* w = which ? kn : qn;
  p[0] = f2b(f0 * sc * w[sub * 4 + 0]);
  p[1] = f2b(f1 * sc * w[sub * 4 + 1]);
  p[2] = f2b(f2v * sc * w[sub * 4 + 2]);
  p[3] = f2b(f3 * sc * w[sub * 4 + 3]);
}

// ---------------------------------------------------------------------------
// Flash attention v4: 128-row Q tiles — each wave carries TWO 16-row Q sets
// (A: q0+wave*16, B: q0+64+wave*16) sharing one K/V staging + barrier pair.
// 36 MFMA per wave-iteration vs 18 (v3) for the same serial skeleton; block
// count and barrier count halve; independent A/B chains double ILP.
// Keeps: reg-prefetch pipeline, key-permuted P/V layouts (k'=(k&15)*4+(k>>4)),
// all strides 68 (2-way b128 reads = free), no-max softmax, L via ones-row.
// ---------------------------------------------------------------------------
#define SKS 68
#define SVS 68
#define SPS 68
__global__ __launch_bounds__(256, 4) void attn_fwd(
    const u16* __restrict__ qkv, const int* __restrict__ cu, u16* __restrict__ out)
{
  __shared__ alignas(16) u16 Ks[64 * SKS];
  __shared__ alignas(16) u16 Vts[66 * SVS];      // rows 0..63 dims, row 64 ones
  __shared__ alignas(16) u16 Ps[8 * 16 * SPS];   // 4 waves x 2 row-sets
  const int seq = blockIdx.z, head = blockIdx.y, qt = blockIdx.x;
  const int start = cu[seq], len = cu[seq + 1] - start;
  const int q0 = qt * 128;
  if (q0 >= len) return;
  const int t = threadIdx.x;
  const int lane = t & 63, wave = t >> 6, quad = lane >> 4, col = lane & 15;

  if (t < 64) Vts[64 * SVS + t] = 0x3F80;        // ones row (bf16 1.0)

  const int rA = q0 + wave * 16 + col, rB = rA + 64;
  const u16* qpA = qkv + (size_t)(start + (rA < len ? rA : len - 1)) * 3072 + head * 64 + quad * 8;
  const u16* qpB = qkv + (size_t)(start + (rB < len ? rB : len - 1)) * 3072 + head * 64 + quad * 8;
  bf16x8 qfA0 = *(const bf16x8*)qpA;
  bf16x8 qfA1 = *(const bf16x8*)(qpA + 32);
  bf16x8 qfB0 = *(const bf16x8*)qpB;
  bf16x8 qfB1 = *(const bf16x8*)(qpB + 32);

  f32x4_t accOA[4] = {}, accOB[4] = {};
  f32x4_t accLA = {}, accLB = {};
  const float SC = 0.125f * 1.44269504089f;

  // staging (r11): sp=t>>3 -> (kc,kh); dc=t&7; key pair (keyA, keyA+16)
  const int sp = t >> 3, dc = t & 7;
  const int kc = sp & 15, kh = sp >> 4;
  const int keyA = kc + 32 * kh;
  u16* ksA = Ks + keyA * SKS + dc * 8;
  u16* ksB = Ks + (keyA + 16) * SKS + dc * 8;
  const int vcol = kc * 4 + 2 * kh;
  const size_t kvbase = 1024 + head * 64 + dc * 8;

  const int nkv = (len + 63) >> 6;
  u32x4_t rkA, rkB, rvA, rvB;
  {   // prologue: tile 0
    int ta = start + (keyA      < len ? keyA      : len - 1);
    int tb = start + (keyA + 16 < len ? keyA + 16 : len - 1);
    const u16* pa = qkv + (size_t)ta * 3072 + kvbase;
    const u16* pb2 = qkv + (size_t)tb * 3072 + kvbase;
    rkA = *(const u32x4*)pa;   rvA = *(const u32x4*)(pa + 1024);
    rkB = *(const u32x4*)pb2;  rvB = *(const u32x4*)(pb2 + 1024);
  }

  for (int it = 0; it < nkv; ++it) {
    const int k0 = it << 6;
    __syncthreads();
    *(u32x4*)ksA = rkA;
    *(u32x4*)ksB = rkB;
    {
      const u16* a = (const u16*)&rvA;
      const u16* b = (const u16*)&rvB;
#pragma unroll
      for (int j = 0; j < 8; ++j) {
        u32 pk = (u32)a[j] | ((u32)b[j] << 16);
        *(u32*)(Vts + (dc * 8 + j) * SVS + vcol) = pk;
      }
    }
    __syncthreads();
    if (it + 1 < nkv) {                          // prefetch next tile
      int kb0 = k0 + 64;
      int ta = start + (kb0 + keyA      < len ? kb0 + keyA      : len - 1);
      int tb = start + (kb0 + keyA + 16 < len ? kb0 + keyA + 16 : len - 1);
      const u16* pa = qkv + (size_t)ta * 3072 + kvbase;
      const u16* pb2 = qkv + (size_t)tb * 3072 + kvbase;
      rkA = *(const u32x4*)pa;   rvA = *(const u32x4*)(pa + 1024);
      rkB = *(const u32x4*)pb2;  rvB = *(const u32x4*)(pb2 + 1024);
    }

    // S = Q.K^T for both row sets (independent chains)
    f32x4_t sgA[4], sgB[4];
#pragma unroll
    for (int g = 0; g < 4; ++g) {
      bf16x8 kb0 = *(const bf16x8*)(Ks + (g*16 + col) * SKS + quad * 8);
      bf16x8 kb1 = *(const bf16x8*)(Ks + (g*16 + col) * SKS + 32 + quad * 8);
      f32x4_t sA = {}, sB = {};
      sA = __builtin_amdgcn_mfma_f32_16x16x32_bf16(qfA0, kb0, sA, 0, 0, 0);
      sB = __builtin_amdgcn_mfma_f32_16x16x32_bf16(qfB0, kb0, sB, 0, 0, 0);
      sA = __builtin_amdgcn_mfma_f32_16x16x32_bf16(qfA1, kb1, sA, 0, 0, 0);
      sB = __builtin_amdgcn_mfma_f32_16x16x32_bf16(qfB1, kb1, sB, 0, 0, 0);
      sgA[g] = sA; sgB[g] = sB;
    }

    // P = exp2(S*SC), masked; key g*16+col -> column col*4+g (b64 rows)
    const bool full = (k0 + 64 <= len);
    bool vg[4];
#pragma unroll
    for (int g = 0; g < 4; ++g) vg[g] = full || (k0 + g*16 + col) < len;
    u16* pwA = Ps + wave * (16 * SPS);
    u16* pwB = Ps + (4 + wave) * (16 * SPS);
#pragma unroll
    for (int r = 0; r < 4; ++r) {
      u16 peA[4], peB[4];
#pragma unroll
      for (int g = 0; g < 4; ++g) {
        float pA = exp2f(sgA[g][r] * SC);
        float pB = exp2f(sgB[g][r] * SC);
        peA[g] = vg[g] ? f2b(pA) : (u16)0;
        peB[g] = vg[g] ? f2b(pB) : (u16)0;
      }
      u32x2_t wA, wB;
      wA[0] = (u32)peA[0] | ((u32)peA[1] << 16);
      wA[1] = (u32)peA[2] | ((u32)peA[3] << 16);
      wB[0] = (u32)peB[0] | ((u32)peB[1] << 16);
      wB[1] = (u32)peB[2] | ((u32)peB[3] << 16);
      *(u32x2*)(pwA + (quad*4 + r) * SPS + col * 4) = wA;
      *(u32x2*)(pwB + (quad*4 + r) * SPS + col * 4) = wB;
    }
    __threadfence_block();

    bf16x8 pfA0 = *(const bf16x8*)(pwA + col * SPS + quad * 8);
    bf16x8 pfA1 = *(const bf16x8*)(pwA + col * SPS + 32 + quad * 8);
    bf16x8 pfB0 = *(const bf16x8*)(pwB + col * SPS + quad * 8);
    bf16x8 pfB1 = *(const bf16x8*)(pwB + col * SPS + 32 + quad * 8);
#pragma unroll
    for (int c = 0; c < 4; ++c) {
      bf16x8 vf0 = *(const bf16x8*)(Vts + (c*16 + col) * SVS + quad * 8);
      bf16x8 vf1 = *(const bf16x8*)(Vts + (c*16 + col) * SVS + 32 + quad * 8);
      accOA[c] = __builtin_amdgcn_mfma_f32_16x16x32_bf16(pfA0, vf0, accOA[c], 0, 0, 0);
      accOB[c] = __builtin_amdgcn_mfma_f32_16x16x32_bf16(pfB0, vf0, accOB[c], 0, 0, 0);
      accOA[c] = __builtin_amdgcn_mfma_f32_16x16x32_bf16(pfA1, vf1, accOA[c], 0, 0, 0);
      accOB[c] = __builtin_amdgcn_mfma_f32_16x16x32_bf16(pfB1, vf1, accOB[c], 0, 0, 0);
    }
    {
      bf16x8 of0 = *(const bf16x8*)(Vts + 64 * SVS + quad * 8);
      bf16x8 of1 = *(const bf16x8*)(Vts + 64 * SVS + 32 + quad * 8);
      accLA = __builtin_amdgcn_mfma_f32_16x16x32_bf16(pfA0, of0, accLA, 0, 0, 0);
      accLB = __builtin_amdgcn_mfma_f32_16x16x32_bf16(pfB0, of0, accLB, 0, 0, 0);
      accLA = __builtin_amdgcn_mfma_f32_16x16x32_bf16(pfA1, of1, accLA, 0, 0, 0);
      accLB = __builtin_amdgcn_mfma_f32_16x16x32_bf16(pfB1, of1, accLB, 0, 0, 0);
    }
  }

#pragma unroll
  for (int r = 0; r < 4; ++r) {
    int rowA = q0 + wave * 16 + quad * 4 + r;
    int rowB = rowA + 64;
    float lA = __shfl(accLA[r], lane & 48);
    float lB = __shfl(accLB[r], lane & 48);
    if (rowA < len) {
      float inv = 1.0f / lA;
      u16* op = out + (size_t)(start + rowA) * 1024 + head * 64 + col;
      op[0]  = f2b(accOA[0][r] * inv);
      op[16] = f2b(accOA[1][r] * inv);
      op[32] = f2b(accOA[2][r] * inv);
      op[48] = f2b(accOA[3][r] * inv);
    }
    if (rowB < len) {
      float inv = 1.0f / lB;
      u16* op = out + (size_t)(start + rowB) * 1024 + head * 64 + col;
      op[0]  = f2b(accOB[0][r] * inv);
      op[16] = f2b(accOB[1][r] * inv);
      op[32] = f2b(accOB[2][r] * inv);
      op[48] = f2b(accOB[3][r] * inv);
    }
  }
}

__global__ void ws_too_small_sentinel(float* out) {
  if (threadIdx.x == 0 && blockIdx.x == 0) out[0] = 1024.0f;
}

// ---------------------------------------------------------------------------
extern "C" void kernel_launch(void* const* d_in, const int* in_sizes, int n_in,
                              void* d_out, int out_size, void* d_ws, size_t ws_size,
                              hipStream_t stream) {
  const float* x  = (const float*)d_in[0];
  const int*   cu = (const int*)d_in[1];
  const float* Wq = (const float*)d_in[2];
  const float* bq = (const float*)d_in[3];
  const float* Wk = (const float*)d_in[4];
  const float* bk = (const float*)d_in[5];
  const float* Wv = (const float*)d_in[6];
  const float* bv = (const float*)d_in[7];
  const float* qn = (const float*)d_in[8];
  const float* kn = (const float*)d_in[9];
  const float* Wo = (const float*)d_in[10];
  const float* bo = (const float*)d_in[11];

  const int T = in_sizes[0] / 1024;
  const int nseq = in_sizes[1] - 1;

  const size_t need_fast = ((size_t)T * 5120 + 4 * WSZ) * 2;   // 92.3 MB @ T=8192
  const size_t need_fall = (size_t)T * 4096 * 2;               // 67.1 MB

  u16* qkv  = (u16*)d_ws;
  u16* attn = qkv + (size_t)T * 3072;
  dim3 blk(256);

  if (ws_size >= need_fast) {
    u16* xb   = attn + (size_t)T * 1024;
    u16* wqkv = xb + (size_t)T * 1024;
    u16* wo   = wqkv + 3 * WSZ;
    cvt_pack<<<dim3(1024), blk, 0, stream>>>(x, Wq, Wk, Wv, Wo, xb, T * 1024);
    gemm_bt2<1, 0><<<dim3((T + 127) / 128, 24), blk, 0, stream>>>(
        xb, wqkv, bq, bk, bv, qn, kn, qkv, T, 1024, 3072);
    attn_fwd<<<dim3(8, 16, nseq), blk, 0, stream>>>(qkv, cu, attn);
    gemm_bt2<0, 1><<<dim3((T + 127) / 128, 8), blk, 0, stream>>>(
        attn, wo, bo, bo, bo, qn, kn, d_out, T, 1024, 1024);
  } else if (ws_size >= need_fall) {
    gemm_bt<1, 0><<<dim3((T + 127) / 128, 24), blk, 0, stream>>>(
        x, Wq, Wk, Wv, bq, bk, bv, qkv, T, 1024, 3072);
    rmsnorm_qk<<<dim3((2 * T * 256 + 255) / 256), blk, 0, stream>>>(qkv, qn, kn, T);
    attn_fwd<<<dim3(8, 16, nseq), blk, 0, stream>>>(qkv, cu, attn);
    gemm_bt<0, 1><<<dim3((T + 127) / 128, 8), blk, 0, stream>>>(
        attn, Wo, Wo, Wo, bo, bo, bo, d_out, T, 1024, 1024);
  } else {
    ws_too_small_sentinel<<<1, 64, 0, stream>>>((float*)d_out);
  }
}